// Round 7
// baseline (382.923 us; speedup 1.0000x reference)
//
#include <hip/hip_runtime.h>
#include <hip/hip_bf16.h>

#define EPSBN 1e-5f
#define NKEYS 110592   // 48^3
#define SLICES 64

typedef __attribute__((ext_vector_type(8))) short bf16x8;
typedef __attribute__((ext_vector_type(4))) float f32x4;

__device__ __forceinline__ float bf2f(ushort u){ return __uint_as_float(((unsigned)u)<<16); }
__device__ __forceinline__ ushort f2bf(float f){
  unsigned u = __float_as_uint(f);
  unsigned r = u + 0x7fffu + ((u>>16)&1u);
  return (ushort)(r>>16);
}

// XOR-swizzled byte offset in row-major [R][KP] bf16 tile (bank-conflict fix).
template<int KP>
__device__ __forceinline__ int swz(int row, int kbyte){
  constexpr int MASK = (KP >= 64) ? 7 : 3;
  return row*(KP*2) + (kbyte ^ ((row & MASK) << 4));
}

__device__ __forceinline__ int tri(int k, int l){
  if (k > l){ int t=k; k=l; l=t; }
  return k*9 - (k*(k-1))/2 + (l-k);
}

// ---------------- zero scratch ----------------
__global__ __launch_bounds__(256) void k_zero(uint4* __restrict__ p, size_t n16){
  size_t i = (size_t)blockIdx.x*256 + threadIdx.x;
  size_t stride = (size_t)gridDim.x*256;
  uint4 z = make_uint4(0,0,0,0);
  for (; i < n16; i += stride) p[i] = z;
}

// ---------------- weight prep: f32 [K][M] -> B-fragment order ----------------
__global__ __launch_bounds__(256) void k_wprep(const float* __restrict__ w,
    ushort* __restrict__ wf, int K, int M){
  int CT = M >> 4;
  int KS = (K + 31) >> 5;
  int total = KS*CT*512;
  for (int idx = blockIdx.x*256 + threadIdx.x; idx < total; idx += gridDim.x*256){
    int e = idx & 7, l = (idx>>3) & 63, c = idx >> 9;
    int ct = c % CT, ks = c / CT;
    int g = l >> 4, j = l & 15;
    int k = ks*32 + g*8 + e, col = ct*16 + j;
    wf[idx] = (k < K) ? f2bf(w[(size_t)k*M + col]) : (ushort)0;
  }
}

// ---------------- voxel unique ----------------
__global__ __launch_bounds__(256) void k_keys(const int* __restrict__ coords,
    unsigned* __restrict__ cnt, int n){
  int i = blockIdx.x*256 + threadIdx.x;
  if (i >= n) return;
  int x = coords[3*i+0], y = coords[3*i+1], z = coords[3*i+2];
  atomicAdd(&cnt[(unsigned)((x*48 + y)*48 + z)], 1u);
}

// pair-scan: flags (occupancy) AND counts, per 1024-key chunk
__global__ __launch_bounds__(256) void k_scan1(const unsigned* __restrict__ cnt,
    unsigned* __restrict__ rloc, unsigned* __restrict__ ploc, unsigned* __restrict__ bsum){
  __shared__ unsigned tf[256], tc[256];
  int t = threadIdx.x;
  int base = blockIdx.x*1024 + t*4;
  uint4 cv = *(const uint4*)&cnt[base];
  unsigned f0 = cv.x?1u:0u, f1 = cv.y?1u:0u, f2 = cv.z?1u:0u, f3 = cv.w?1u:0u;
  unsigned sf = f0+f1+f2+f3;
  unsigned sc = cv.x+cv.y+cv.z+cv.w;
  tf[t] = sf; tc[t] = sc;
  __syncthreads();
  for (int off=1; off<256; off<<=1){
    unsigned af = (t>=off) ? tf[t-off] : 0u;
    unsigned ac = (t>=off) ? tc[t-off] : 0u;
    __syncthreads();
    tf[t] += af; tc[t] += ac;
    __syncthreads();
  }
  unsigned rf = tf[t] - sf, rc = tc[t] - sc;
  rloc[base+0] = rf; rf += f0;    ploc[base+0] = rc; rc += cv.x;
  rloc[base+1] = rf; rf += f1;    ploc[base+1] = rc; rc += cv.y;
  rloc[base+2] = rf; rf += f2;    ploc[base+2] = rc; rc += cv.z;
  rloc[base+3] = rf;              ploc[base+3] = rc;
  if (t == 255){ bsum[2*blockIdx.x] = tf[255]; bsum[2*blockIdx.x+1] = tc[255]; }
}

__global__ __launch_bounds__(128) void k_scan2(const unsigned* __restrict__ bsum,
    unsigned* __restrict__ boff){
  __shared__ unsigned tf[128], tc[128];
  int t = threadIdx.x;
  unsigned vf = (t < 108) ? bsum[2*t] : 0u;
  unsigned vc = (t < 108) ? bsum[2*t+1] : 0u;
  tf[t] = vf; tc[t] = vc;
  __syncthreads();
  for (int off=1; off<128; off<<=1){
    unsigned af = (t>=off) ? tf[t-off] : 0u;
    unsigned ac = (t>=off) ? tc[t-off] : 0u;
    __syncthreads();
    tf[t] += af; tc[t] += ac;
    __syncthreads();
  }
  boff[2*t] = tf[t] - vf;     // flag-offset; boff[216] = total M
  boff[2*t+1] = tc[t] - vc;   // count-offset
}

// unique rows + per-voxel CSR geometry (start, count)
__global__ __launch_bounds__(256) void k_unq(const unsigned* __restrict__ cnt,
    const unsigned* __restrict__ rloc, const unsigned* __restrict__ ploc,
    const unsigned* __restrict__ boff, float* __restrict__ unq,
    unsigned* __restrict__ vst, unsigned* __restrict__ vct){
  int k = blockIdx.x*256 + threadIdx.x;
  if (k >= NKEYS) return;
  unsigned c = cnt[k];
  if (c == 0) return;
  unsigned r  = rloc[k] + boff[2*(k>>10)];
  unsigned st = ploc[k] + boff[2*(k>>10)+1];
  float z = (float)(k % 48);
  float y = (float)((k/48) % 48);
  float x = (float)(k / 2304);
  unq[3*(size_t)r+0] = x; unq[3*(size_t)r+1] = y; unq[3*(size_t)r+2] = z;
  vst[r] = st; vct[r] = c;
}

__global__ __launch_bounds__(256) void k_pad(const unsigned* __restrict__ boff,
    float* __restrict__ unq, int n){
  int i = blockIdx.x*256 + threadIdx.x;
  if (i >= n) return;
  if ((unsigned)i >= boff[216]){
    unq[3*(size_t)i+0] = -1.f; unq[3*(size_t)i+1] = -1.f; unq[3*(size_t)i+2] = -1.f;
  }
}

// place each point into its voxel's CSR slot
__global__ __launch_bounds__(256) void k_csr(const int* __restrict__ coords,
    const unsigned* __restrict__ ploc, const unsigned* __restrict__ boff,
    unsigned* __restrict__ cursor, unsigned* __restrict__ csr, int n){
  int i = blockIdx.x*256 + threadIdx.x;
  if (i >= n) return;
  int x = coords[3*i+0], y = coords[3*i+1], z = coords[3*i+2];
  unsigned k = (unsigned)((x*48 + y)*48 + z);
  unsigned slot = atomicAdd(&cursor[k], 1u);
  unsigned st = ploc[k] + boff[2*(k>>10)+1];
  csr[st + slot] = i;
}

// ---------------- feats moments: s[9] = sum x, q[45] = sum x_k x_l (k<=l) ----------------
__global__ __launch_bounds__(256) void k_stats0x(const float* __restrict__ X,
    float* __restrict__ slices, int n){
  float s[9], q[45];
  #pragma unroll
  for (int k=0;k<9;k++) s[k]=0.f;
  #pragma unroll
  for (int i=0;i<45;i++) q[i]=0.f;
  int stride = gridDim.x*256;
  for (int i = blockIdx.x*256 + threadIdx.x; i < n; i += stride){
    float v[9];
    #pragma unroll
    for (int k=0;k<9;k++) v[k] = X[(size_t)i*9+k];
    int qi=0;
    #pragma unroll
    for (int k=0;k<9;k++){
      s[k] += v[k];
      #pragma unroll
      for (int l=k;l<9;l++) q[qi++] += v[k]*v[l];
    }
  }
  #pragma unroll
  for (int off=32; off>0; off>>=1){
    #pragma unroll
    for (int k=0;k<9;k++)  s[k] += __shfl_down(s[k], off, 64);
    #pragma unroll
    for (int i=0;i<45;i++) q[i] += __shfl_down(q[i], off, 64);
  }
  if ((threadIdx.x & 63) == 0){
    float* sl = slices + (size_t)(blockIdx.x & (SLICES-1))*54;
    #pragma unroll
    for (int k=0;k<9;k++)  atomicAdd(&sl[k],   s[k]);
    #pragma unroll
    for (int i=0;i<45;i++) atomicAdd(&sl[9+i], q[i]);
  }
}

// ---------------- ac0 + analytic ac1 from feats moments ----------------
__global__ void k_fin01(const float* __restrict__ slices, float invN,
    const float* __restrict__ g0, const float* __restrict__ b0,
    const float* __restrict__ g1, const float* __restrict__ b1,
    const float* __restrict__ w1, float* __restrict__ ac0, float* __restrict__ ac1){
  __shared__ float red[54];
  int t = threadIdx.x;   // 64 threads
  if (t < 54){
    float a = 0.f;
    for (int sl=0; sl<SLICES; sl++) a += slices[(size_t)sl*54 + t];
    red[t] = a;
  }
  __syncthreads();
  float m[9], a0[9], c0[9], qb[45];
  #pragma unroll
  for (int k=0;k<9;k++) m[k] = red[k]*invN;
  #pragma unroll
  for (int i=0;i<45;i++) qb[i] = red[9+i]*invN;
  #pragma unroll
  for (int k=0;k<9;k++){
    float var = qb[tri(k,k)] - m[k]*m[k];
    a0[k] = g0[k]*rsqrtf(var + EPSBN);
    c0[k] = b0[k] - m[k]*a0[k];
  }
  if (t < 9){ ac0[t] = a0[t]; ac0[9+t] = c0[t]; }
  float wj[9];
  #pragma unroll
  for (int k=0;k<9;k++) wj[k] = w1[(size_t)k*64 + t];
  float mean = 0.f;
  #pragma unroll
  for (int k=0;k<9;k++) mean += (m[k]*a0[k] + c0[k])*wj[k];
  float e2 = 0.f;
  #pragma unroll
  for (int k=0;k<9;k++)
    #pragma unroll
    for (int l=0;l<9;l++){
      float U = a0[k]*a0[l]*qb[tri(k,l)] + a0[k]*c0[l]*m[k] + a0[l]*c0[k]*m[l] + c0[k]*c0[l];
      e2 += wj[k]*wj[l]*U;
    }
  float var = e2 - mean*mean;
  float a = g1[t]*rsqrtf(var + EPSBN);
  ac1[t] = a;
  ac1[64+t] = b1[t] - mean*a;
}

// reduce slices -> a = g*rsqrt(var+eps), c = b - mean*a.  Stats over RAW
// (bias-free) pre-BN activations; linear bias cancels in training-mode BN.
__global__ void k_fin(const float* __restrict__ slices, int M, float invN,
    const float* __restrict__ g, const float* __restrict__ b, float* __restrict__ ac){
  int j = blockIdx.x*64 + threadIdx.x;
  if (j >= M) return;
  float s = 0.f, ss = 0.f;
  for (int sl = 0; sl < SLICES; sl++){
    s  += slices[(size_t)sl*2*M + j];
    ss += slices[(size_t)sl*2*M + M + j];
  }
  float mean = s*invN;
  float var = ss*invN - mean*mean;
  float a = g[j]*rsqrtf(var + EPSBN);
  ac[j] = a;
  ac[M+j] = b[j] - mean*a;
}

// ---------------- fused MFMA recompute chain, barrier-free weight streaming ----------------
// 64 rows/block, 4 waves. DEPTH=2: t2 stats. DEPTH=3: t3 stats. DEPTH=4: dense y4 store.
template<int DEPTH>
__global__ __launch_bounds__(256,2) void k_chain(
    const float* __restrict__ feats, const float* __restrict__ ac0,
    const ushort* __restrict__ w1f, const float* __restrict__ ac1,
    const ushort* __restrict__ w2f, const float* __restrict__ ac2,
    const ushort* __restrict__ w3f, const float* __restrict__ ac3,
    const ushort* __restrict__ w4f, const float* __restrict__ b4,
    ushort* __restrict__ y4, float* __restrict__ slices, int n){
  constexpr int SMEM = (DEPTH==2) ? 12288 : (DEPTH==3) ? 28672 : 32768;
  __shared__ __align__(16) char smem[SMEM];
  char* X0 = smem;                  // [64][32]  bf16 swz<32>,  4KB

  int t = threadIdx.x;
  int lane = t & 63, w = t >> 6;
  int lrow = lane & 15, lgrp = lane >> 4;
  int rowbase = blockIdx.x * 64;

  // stage-1 B-frag (issued before staging; overlaps)
  bf16x8 b1 = *(const bf16x8*)(w1f + (size_t)(w*64 + lane)*8);

  // ---- X0 = bn0(feats), K padded to 32, rows >= n zeroed ----
  for (int e = t; e < 2048; e += 256){
    int row = e >> 5, k = e & 31;
    int gr = rowbase + row;
    float v = (k < 9 && gr < n) ? fmaf(feats[(size_t)gr*9 + k], ac0[k], ac0[9+k]) : 0.f;
    *(ushort*)(X0 + swz<32>(row, k*2)) = f2bf(v);
  }
  __syncthreads();

  // ---- stage 1: t1 = X0 @ w1 (wave w: cols 16w..16w+16) ----
  f32x4 acc0[4] = {};
  #pragma unroll
  for (int rb = 0; rb < 4; rb++){
    bf16x8 a = *(const bf16x8*)(X0 + swz<32>(rb*16 + lrow, lgrp*16));
    acc0[rb] = __builtin_amdgcn_mfma_f32_16x16x32_bf16(a, b1, acc0[rb], 0,0,0);
  }

  char* T1 = smem + 4096;           // [64][64] bf16 swz<64>, 8KB
  // ---- T1 = bf16(relu(bn1(t1))), rows >= n zeroed ----
  {
    int j = w*16 + lrow;
    float a1 = ac1[j], c1 = ac1[64+j];
    #pragma unroll
    for (int rb=0;rb<4;rb++)
      #pragma unroll
      for (int r=0;r<4;r++){
        int row = rb*16 + 4*lgrp + r;
        float v = fmaxf(fmaf(acc0[rb][r], a1, c1), 0.f);
        if (rowbase + row >= n) v = 0.f;
        *(ushort*)(T1 + swz<64>(row, j*2)) = f2bf(v);
      }
  }
  __syncthreads();

  // ---- stage 2: 64x64 @ 64x128 (wave w: cols 32w..32w+32) ----
  f32x4 acc1[4][2] = {};
  #pragma unroll
  for (int ks=0; ks<2; ks++){
    bf16x8 bb[2];
    #pragma unroll
    for (int f=0;f<2;f++)
      bb[f] = *(const bf16x8*)(w2f + (size_t)((ks*8 + 2*w + f)*64 + lane)*8);
    #pragma unroll
    for (int rb=0;rb<4;rb++){
      bf16x8 a = *(const bf16x8*)(T1 + swz<64>(rb*16 + lrow, ks*64 + lgrp*16));
      #pragma unroll
      for (int f=0;f<2;f++)
        acc1[rb][f] = __builtin_amdgcn_mfma_f32_16x16x32_bf16(a, bb[f], acc1[rb][f], 0,0,0);
    }
  }

  if constexpr (DEPTH == 2){
    float s[2]={0.f,0.f}, ss[2]={0.f,0.f};
    #pragma unroll
    for (int rb=0;rb<4;rb++)
      #pragma unroll
      for (int f=0;f<2;f++)
        #pragma unroll
        for (int r=0;r<4;r++){ float v=acc1[rb][f][r]; s[f]+=v; ss[f]+=v*v; }
    __syncthreads();
    float* ssum = (float*)smem;
    ssum[t] = 0.f;
    __syncthreads();
    #pragma unroll
    for (int f=0;f<2;f++){
      int j = w*32 + 16*f + lrow;
      atomicAdd(&ssum[j], s[f]); atomicAdd(&ssum[128+j], ss[f]);
    }
    __syncthreads();
    float* gsl = slices + (size_t)(blockIdx.x & (SLICES-1))*256;
    atomicAdd(&gsl[t], ssum[t]);
    return;
  }

  if constexpr (DEPTH >= 3){
  char* T2 = smem + 12288;          // [64][128] bf16 swz<128>, 16KB
  // ---- T2 = bf16(relu(bn2(t2))), rows >= n zeroed ----
  #pragma unroll
  for (int f=0;f<2;f++){
    int j = w*32 + 16*f + lrow;
    float a2 = ac2[j], c2 = ac2[128+j];
    #pragma unroll
    for (int rb=0;rb<4;rb++)
      #pragma unroll
      for (int r=0;r<4;r++){
        int row = rb*16 + 4*lgrp + r;
        float v = fmaxf(fmaf(acc1[rb][f][r], a2, c2), 0.f);
        if (rowbase + row >= n) v = 0.f;
        *(ushort*)(T2 + swz<128>(row, j*2)) = f2bf(v);
      }
  }
  __syncthreads();

  if constexpr (DEPTH == 3){
    // ---- stage 3 (stats only): two 32-col halves to cap VGPR ----
    float s3[2][2], ss3[2][2];
    #pragma unroll
    for (int h=0; h<2; h++){
      f32x4 acc2[4][2] = {};
      #pragma unroll
      for (int ks=0; ks<4; ks++){
        bf16x8 bb[2];
        #pragma unroll
        for (int f=0;f<2;f++)
          bb[f] = *(const bf16x8*)(w3f + (size_t)((ks*16 + 4*w + 2*h + f)*64 + lane)*8);
        #pragma unroll
        for (int rb=0;rb<4;rb++){
          bf16x8 a = *(const bf16x8*)(T2 + swz<128>(rb*16 + lrow, ks*64 + lgrp*16));
          #pragma unroll
          for (int f=0;f<2;f++)
            acc2[rb][f] = __builtin_amdgcn_mfma_f32_16x16x32_bf16(a, bb[f], acc2[rb][f], 0,0,0);
        }
      }
      #pragma unroll
      for (int f=0;f<2;f++){
        float s=0.f, ss=0.f;
        #pragma unroll
        for (int rb=0;rb<4;rb++)
          #pragma unroll
          for (int r=0;r<4;r++){ float v=acc2[rb][f][r]; s+=v; ss+=v*v; }
        s3[h][f]=s; ss3[h][f]=ss;
      }
    }
    __syncthreads();
    float* ssum = (float*)smem;
    for (int e=t; e<512; e+=256) ssum[e] = 0.f;
    __syncthreads();
    #pragma unroll
    for (int h=0;h<2;h++)
      #pragma unroll
      for (int f=0;f<2;f++){
        int j = 64*w + 32*h + 16*f + lrow;
        atomicAdd(&ssum[j], s3[h][f]); atomicAdd(&ssum[256+j], ss3[h][f]);
      }
    __syncthreads();
    float* gsl = slices + (size_t)(blockIdx.x & (SLICES-1))*512;
    for (int e=t; e<512; e+=256) atomicAdd(&gsl[e], ssum[e]);
    return;
  }

  if constexpr (DEPTH == 4){
  // ---- stage 3 full into registers: wave w owns cols 64w..64w+64 ----
  f32x4 acc2[4][4] = {};
  #pragma unroll
  for (int ks=0; ks<4; ks++){
    bf16x8 bb[4];
    #pragma unroll
    for (int f=0;f<4;f++)
      bb[f] = *(const bf16x8*)(w3f + (size_t)((ks*16 + 4*w + f)*64 + lane)*8);
    #pragma unroll
    for (int rb=0;rb<4;rb++){
      bf16x8 a = *(const bf16x8*)(T2 + swz<128>(rb*16 + lrow, ks*64 + lgrp*16));
      #pragma unroll
      for (int f=0;f<4;f++)
        acc2[rb][f] = __builtin_amdgcn_mfma_f32_16x16x32_bf16(a, bb[f], acc2[rb][f], 0,0,0);
    }
  }
  __syncthreads();   // T2 (and X0/T1) dead -> X3 aliases smem base

  // ---- X3 = bf16(relu(bn3(t3))) at smem+0, [64][256] swz<256>, 32KB ----
  char* X3 = smem;
  #pragma unroll
  for (int f=0;f<4;f++){
    int j = 64*w + 16*f + lrow;
    float a3 = ac3[j], c3 = ac3[256+j];
    #pragma unroll
    for (int rb=0;rb<4;rb++)
      #pragma unroll
      for (int r=0;r<4;r++){
        int row = rb*16 + 4*lgrp + r;
        float v = fmaxf(fmaf(acc2[rb][f][r], a3, c3), 0.f);
        if (rowbase + row >= n) v = 0.f;
        *(ushort*)(X3 + swz<256>(row, j*2)) = f2bf(v);
      }
  }
  __syncthreads();

  // ---- stage 4: 64x256 @ 256x64 (wave w: cols 16w..16w+16) ----
  f32x4 acc3[4] = {};
  #pragma unroll
  for (int ks=0; ks<8; ks++){
    bf16x8 b = *(const bf16x8*)(w4f + (size_t)((ks*4 + w)*64 + lane)*8);
    #pragma unroll
    for (int rb=0;rb<4;rb++){
      bf16x8 a = *(const bf16x8*)(X3 + swz<256>(rb*16 + lrow, ks*64 + lgrp*16));
      acc3[rb] = __builtin_amdgcn_mfma_f32_16x16x32_bf16(a, b, acc3[rb], 0,0,0);
    }
  }

  // ---- dense store: y4[gr][j] = t4 + b4 (no atomics) ----
  {
    int j = w*16 + lrow;
    float bias4 = b4[j];
    #pragma unroll
    for (int rb=0;rb<4;rb++)
      #pragma unroll
      for (int r=0;r<4;r++){
        int gr = rowbase + 16*rb + 4*lgrp + r;
        if (gr < n) y4[(size_t)gr*64 + j] = f2bf(acc3[rb][r] + bias4);
      }
  }
  } // DEPTH==4
  } // DEPTH>=3
}

// ---------------- pool (gather max per voxel) + projection, fused ----------------
// 4 waves/block, one voxel per wave; lane j = channel j.
__global__ __launch_bounds__(256) void k_pool(const ushort* __restrict__ y4,
    const unsigned* __restrict__ csr, const unsigned* __restrict__ vst,
    const unsigned* __restrict__ vct, const unsigned* __restrict__ boff,
    const float* __restrict__ wp, const float* __restrict__ bp,
    float* __restrict__ out, int n){
  __shared__ float wps[1024];       // wp [64][16]
  __shared__ float sm[4][64];
  int t = threadIdx.x, w = t >> 6, lane = t & 63;
  for (int e=t; e<1024; e+=256) wps[e] = wp[e];
  int r = blockIdx.x*4 + w;
  unsigned M = boff[216];
  if (r < n){
    float m;
    if (r < (int)M){
      unsigned st = vst[r], c = vct[r];
      unsigned nc = c < 64u ? c : 64u;
      unsigned pi_l = (lane < nc) ? csr[st + lane] : 0u;
      m = -__builtin_inff();
      for (unsigned p=0; p<nc; p++){
        unsigned pi = __shfl(pi_l, (int)p, 64);
        m = fmaxf(m, bf2f(y4[(size_t)pi*64 + lane]));
      }
      for (unsigned p=nc; p<c; p++){         // rare overflow path
        unsigned pi = csr[st + p];
        m = fmaxf(m, bf2f(y4[(size_t)pi*64 + lane]));
      }
    } else {
      m = 0.f;                               // padding voxel: pooled = 0
    }
    sm[w][lane] = m;
  }
  __syncthreads();
  if (r < n && lane < 16){
    float acc = bp[lane];
    #pragma unroll 8
    for (int j=0; j<64; j++) acc = fmaf(sm[w][j], wps[j*16 + lane], acc);
    out[(size_t)r*16 + lane] = fmaxf(acc, 0.f);
  }
}

extern "C" void kernel_launch(void* const* d_in, const int* in_sizes, int n_in,
                              void* d_out, int out_size, void* d_ws, size_t ws_size,
                              hipStream_t stream){
  (void)n_in; (void)out_size;
  const float* feats  = (const float*)d_in[0];
  const int*   coords = (const int*)d_in[1];
  const float* g0=(const float*)d_in[2];  const float* bb0=(const float*)d_in[3];
  const float* g1=(const float*)d_in[4];  const float* bb1=(const float*)d_in[5];
  const float* g2=(const float*)d_in[6];  const float* bb2=(const float*)d_in[7];
  const float* g3=(const float*)d_in[8];  const float* bb3=(const float*)d_in[9];
  const float* w1=(const float*)d_in[10];
  const float* w2=(const float*)d_in[12];
  const float* w3=(const float*)d_in[14];
  const float* w4=(const float*)d_in[16]; const float* b4=(const float*)d_in[17];
  const float* wp=(const float*)d_in[18]; const float* bp=(const float*)d_in[19];
  int n = in_sizes[0]/9;

  char* ws = (char*)d_ws;
  size_t off = 0;
  auto alloc = [&](size_t bytes){ size_t o = off; off = (off + bytes + 255) & ~(size_t)255; return o; };
  size_t o_cnt  = alloc((size_t)NKEYS*4);            // zeroed
  size_t o_cur  = alloc((size_t)NKEYS*4);            // zeroed (csr cursors)
  size_t o_sl0  = alloc((size_t)SLICES*54*4);        // zeroed
  size_t o_sl2  = alloc((size_t)SLICES*256*4);       // zeroed
  size_t o_sl3  = alloc((size_t)SLICES*512*4);       // zeroed
  size_t zero_end = off;
  size_t o_rloc = alloc((size_t)NKEYS*4);
  size_t o_ploc = alloc((size_t)NKEYS*4);
  size_t o_bsum = alloc(256*4);
  size_t o_boff = alloc(256*4);
  size_t o_ac0  = alloc(18*4);
  size_t o_ac1  = alloc(128*4);
  size_t o_ac2  = alloc(256*4);
  size_t o_ac3  = alloc(512*4);
  size_t o_w1f  = alloc(2048*2);
  size_t o_w2f  = alloc(8192*2);
  size_t o_w3f  = alloc(32768*2);
  size_t o_w4f  = alloc(16384*2);
  size_t o_csr  = alloc((size_t)n*4);
  size_t o_vst  = alloc((size_t)n*4);
  size_t o_vct  = alloc((size_t)n*4);
  size_t o_y4   = alloc((size_t)n*64*2);
  if (ws_size < off) return;                         // clean fail if ws too small

  unsigned* cnt  = (unsigned*)(ws + o_cnt);
  unsigned* cursor = (unsigned*)(ws + o_cur);
  unsigned* rloc = (unsigned*)(ws + o_rloc);
  unsigned* ploc = (unsigned*)(ws + o_ploc);
  unsigned* bsum = (unsigned*)(ws + o_bsum);
  unsigned* boff = (unsigned*)(ws + o_boff);
  float* sl0 = (float*)(ws + o_sl0);
  float* sl2 = (float*)(ws + o_sl2);
  float* sl3 = (float*)(ws + o_sl3);
  float* ac0 = (float*)(ws + o_ac0);
  float* ac1 = (float*)(ws + o_ac1);
  float* ac2 = (float*)(ws + o_ac2);
  float* ac3 = (float*)(ws + o_ac3);
  ushort* w1f = (ushort*)(ws + o_w1f);
  ushort* w2f = (ushort*)(ws + o_w2f);
  ushort* w3f = (ushort*)(ws + o_w3f);
  ushort* w4f = (ushort*)(ws + o_w4f);
  unsigned* csr = (unsigned*)(ws + o_csr);
  unsigned* vst = (unsigned*)(ws + o_vst);
  unsigned* vct = (unsigned*)(ws + o_vct);
  ushort* y4 = (ushort*)(ws + o_y4);

  float* out_pool = (float*)d_out;
  float* out_unq  = out_pool + (size_t)n*16;

  {
    size_t n16 = zero_end/16;
    int zb = (int)((n16 + 255)/256); if (zb > 2048) zb = 2048;
    k_zero<<<zb,256,0,stream>>>((uint4*)ws, n16);
  }

  // weight prep (bf16, B-fragment order)
  k_wprep<<<8,256,0,stream>>>(w1, w1f, 9, 64);
  k_wprep<<<32,256,0,stream>>>(w2, w2f, 64, 128);
  k_wprep<<<128,256,0,stream>>>(w3, w3f, 128, 256);
  k_wprep<<<64,256,0,stream>>>(w4, w4f, 256, 64);

  int nb = (n + 255)/256;
  k_keys<<<nb,256,0,stream>>>(coords, cnt, n);
  k_scan1<<<NKEYS/1024,256,0,stream>>>(cnt, rloc, ploc, bsum);
  k_scan2<<<1,128,0,stream>>>(bsum, boff);
  k_unq<<<(NKEYS+255)/256,256,0,stream>>>(cnt, rloc, ploc, boff, out_unq, vst, vct);
  k_pad<<<nb,256,0,stream>>>(boff, out_unq, n);
  k_csr<<<nb,256,0,stream>>>(coords, ploc, boff, cursor, csr, n);

  // feats moments -> ac0 + analytic ac1
  k_stats0x<<<512,256,0,stream>>>(feats, sl0, n);
  k_fin01<<<1,64,0,stream>>>(sl0, 1.f/(float)n, g0, bb0, g1, bb1, w1, ac0, ac1);

  int gb = (n+63)/64;
  k_chain<2><<<gb,256,0,stream>>>(feats, ac0, w1f, ac1, w2f, ac2, w3f, ac3, w4f, b4, nullptr, sl2, n);
  k_fin<<<2,64,0,stream>>>(sl2, 128, 1.f/(float)n, g2, bb2, ac2);

  k_chain<3><<<gb,256,0,stream>>>(feats, ac0, w1f, ac1, w2f, ac2, w3f, ac3, w4f, b4, nullptr, sl3, n);
  k_fin<<<4,64,0,stream>>>(sl3, 256, 1.f/(float)n, g3, bb3, ac3);

  k_chain<4><<<gb,256,0,stream>>>(feats, ac0, w1f, ac1, w2f, ac2, w3f, ac3, w4f, b4, y4, nullptr, n);

  k_pool<<<(n+3)/4,256,0,stream>>>(y4, csr, vst, vct, boff, wp, bp, out_pool, n);
}

// Round 8
// 366.120 us; speedup vs baseline: 1.0459x; 1.0459x over previous
//
#include <hip/hip_runtime.h>
#include <hip/hip_bf16.h>

#define EPSBN 1e-5f
#define NKEYS 110592   // 48^3
#define SLICES 64

typedef __attribute__((ext_vector_type(8))) short bf16x8;
typedef __attribute__((ext_vector_type(4))) float f32x4;

__device__ __forceinline__ float bf2f(ushort u){ return __uint_as_float(((unsigned)u)<<16); }
__device__ __forceinline__ ushort f2bf(float f){
  unsigned u = __float_as_uint(f);
  unsigned r = u + 0x7fffu + ((u>>16)&1u);
  return (ushort)(r>>16);
}

// XOR-swizzled byte offset in row-major [R][KP] bf16 tile (bank-conflict fix).
template<int KP>
__device__ __forceinline__ int swz(int row, int kbyte){
  constexpr int MASK = (KP >= 64) ? 7 : 3;
  return row*(KP*2) + (kbyte ^ ((row & MASK) << 4));
}

__device__ __forceinline__ int tri(int k, int l){
  if (k > l){ int t=k; k=l; l=t; }
  return k*9 - (k*(k-1))/2 + (l-k);
}

// ---------------- zero scratch ----------------
__global__ __launch_bounds__(256) void k_zero(uint4* __restrict__ p, size_t n16){
  size_t i = (size_t)blockIdx.x*256 + threadIdx.x;
  size_t stride = (size_t)gridDim.x*256;
  uint4 z = make_uint4(0,0,0,0);
  for (; i < n16; i += stride) p[i] = z;
}

// ---------------- weight prep: f32 [K][M] -> B-fragment order ----------------
__global__ __launch_bounds__(256) void k_wprep(const float* __restrict__ w,
    ushort* __restrict__ wf, int K, int M){
  int CT = M >> 4;
  int KS = (K + 31) >> 5;
  int total = KS*CT*512;
  for (int idx = blockIdx.x*256 + threadIdx.x; idx < total; idx += gridDim.x*256){
    int e = idx & 7, l = (idx>>3) & 63, c = idx >> 9;
    int ct = c % CT, ks = c / CT;
    int g = l >> 4, j = l & 15;
    int k = ks*32 + g*8 + e, col = ct*16 + j;
    wf[idx] = (k < K) ? f2bf(w[(size_t)k*M + col]) : (ushort)0;
  }
}

// ---------------- voxel unique ----------------
__global__ __launch_bounds__(256) void k_keys(const int* __restrict__ coords,
    unsigned* __restrict__ cnt, int n){
  int i = blockIdx.x*256 + threadIdx.x;
  if (i >= n) return;
  int x = coords[3*i+0], y = coords[3*i+1], z = coords[3*i+2];
  atomicAdd(&cnt[(unsigned)((x*48 + y)*48 + z)], 1u);
}

// pair-scan: flags (occupancy) AND counts, per 1024-key chunk
__global__ __launch_bounds__(256) void k_scan1(const unsigned* __restrict__ cnt,
    unsigned* __restrict__ rloc, unsigned* __restrict__ ploc, unsigned* __restrict__ bsum){
  __shared__ unsigned tf[256], tc[256];
  int t = threadIdx.x;
  int base = blockIdx.x*1024 + t*4;
  uint4 cv = *(const uint4*)&cnt[base];
  unsigned f0 = cv.x?1u:0u, f1 = cv.y?1u:0u, f2 = cv.z?1u:0u, f3 = cv.w?1u:0u;
  unsigned sf = f0+f1+f2+f3;
  unsigned sc = cv.x+cv.y+cv.z+cv.w;
  tf[t] = sf; tc[t] = sc;
  __syncthreads();
  for (int off=1; off<256; off<<=1){
    unsigned af = (t>=off) ? tf[t-off] : 0u;
    unsigned ac = (t>=off) ? tc[t-off] : 0u;
    __syncthreads();
    tf[t] += af; tc[t] += ac;
    __syncthreads();
  }
  unsigned rf = tf[t] - sf, rc = tc[t] - sc;
  rloc[base+0] = rf; rf += f0;    ploc[base+0] = rc; rc += cv.x;
  rloc[base+1] = rf; rf += f1;    ploc[base+1] = rc; rc += cv.y;
  rloc[base+2] = rf; rf += f2;    ploc[base+2] = rc; rc += cv.z;
  rloc[base+3] = rf;              ploc[base+3] = rc;
  if (t == 255){ bsum[2*blockIdx.x] = tf[255]; bsum[2*blockIdx.x+1] = tc[255]; }
}

__global__ __launch_bounds__(128) void k_scan2(const unsigned* __restrict__ bsum,
    unsigned* __restrict__ boff){
  __shared__ unsigned tf[128], tc[128];
  int t = threadIdx.x;
  unsigned vf = (t < 108) ? bsum[2*t] : 0u;
  unsigned vc = (t < 108) ? bsum[2*t+1] : 0u;
  tf[t] = vf; tc[t] = vc;
  __syncthreads();
  for (int off=1; off<128; off<<=1){
    unsigned af = (t>=off) ? tf[t-off] : 0u;
    unsigned ac = (t>=off) ? tc[t-off] : 0u;
    __syncthreads();
    tf[t] += af; tc[t] += ac;
    __syncthreads();
  }
  boff[2*t] = tf[t] - vf;     // flag-offset; boff[216] = total M
  boff[2*t+1] = tc[t] - vc;   // count-offset
}

// unique rows + per-voxel CSR geometry (start, count)
__global__ __launch_bounds__(256) void k_unq(const unsigned* __restrict__ cnt,
    const unsigned* __restrict__ rloc, const unsigned* __restrict__ ploc,
    const unsigned* __restrict__ boff, float* __restrict__ unq,
    unsigned* __restrict__ vst, unsigned* __restrict__ vct){
  int k = blockIdx.x*256 + threadIdx.x;
  if (k >= NKEYS) return;
  unsigned c = cnt[k];
  if (c == 0) return;
  unsigned r  = rloc[k] + boff[2*(k>>10)];
  unsigned st = ploc[k] + boff[2*(k>>10)+1];
  float z = (float)(k % 48);
  float y = (float)((k/48) % 48);
  float x = (float)(k / 2304);
  unq[3*(size_t)r+0] = x; unq[3*(size_t)r+1] = y; unq[3*(size_t)r+2] = z;
  vst[r] = st; vct[r] = c;
}

// place each point into its voxel's CSR slot
__global__ __launch_bounds__(256) void k_csr(const int* __restrict__ coords,
    const unsigned* __restrict__ ploc, const unsigned* __restrict__ boff,
    unsigned* __restrict__ cursor, unsigned* __restrict__ csr, int n){
  int i = blockIdx.x*256 + threadIdx.x;
  if (i >= n) return;
  int x = coords[3*i+0], y = coords[3*i+1], z = coords[3*i+2];
  unsigned k = (unsigned)((x*48 + y)*48 + z);
  unsigned slot = atomicAdd(&cursor[k], 1u);
  unsigned st = ploc[k] + boff[2*(k>>10)+1];
  csr[st + slot] = i;
}

// ---------------- feats moments: s[9] = sum x, q[45] = sum x_k x_l (k<=l) ----------------
__global__ __launch_bounds__(256) void k_stats0x(const float* __restrict__ X,
    float* __restrict__ slices, int n){
  float s[9], q[45];
  #pragma unroll
  for (int k=0;k<9;k++) s[k]=0.f;
  #pragma unroll
  for (int i=0;i<45;i++) q[i]=0.f;
  int stride = gridDim.x*256;
  for (int i = blockIdx.x*256 + threadIdx.x; i < n; i += stride){
    float v[9];
    #pragma unroll
    for (int k=0;k<9;k++) v[k] = X[(size_t)i*9+k];
    int qi=0;
    #pragma unroll
    for (int k=0;k<9;k++){
      s[k] += v[k];
      #pragma unroll
      for (int l=k;l<9;l++) q[qi++] += v[k]*v[l];
    }
  }
  #pragma unroll
  for (int off=32; off>0; off>>=1){
    #pragma unroll
    for (int k=0;k<9;k++)  s[k] += __shfl_down(s[k], off, 64);
    #pragma unroll
    for (int i=0;i<45;i++) q[i] += __shfl_down(q[i], off, 64);
  }
  if ((threadIdx.x & 63) == 0){
    float* sl = slices + (size_t)(blockIdx.x & (SLICES-1))*54;
    #pragma unroll
    for (int k=0;k<9;k++)  atomicAdd(&sl[k],   s[k]);
    #pragma unroll
    for (int i=0;i<45;i++) atomicAdd(&sl[9+i], q[i]);
  }
}

// ---------------- ac0 + analytic ac1 from feats moments ----------------
__global__ void k_fin01(const float* __restrict__ slices, float invN,
    const float* __restrict__ g0, const float* __restrict__ b0,
    const float* __restrict__ g1, const float* __restrict__ b1,
    const float* __restrict__ w1, float* __restrict__ ac0, float* __restrict__ ac1){
  __shared__ float red[54];
  int t = threadIdx.x;   // 64 threads
  if (t < 54){
    float a = 0.f;
    for (int sl=0; sl<SLICES; sl++) a += slices[(size_t)sl*54 + t];
    red[t] = a;
  }
  __syncthreads();
  float m[9], a0[9], c0[9], qb[45];
  #pragma unroll
  for (int k=0;k<9;k++) m[k] = red[k]*invN;
  #pragma unroll
  for (int i=0;i<45;i++) qb[i] = red[9+i]*invN;
  #pragma unroll
  for (int k=0;k<9;k++){
    float var = qb[tri(k,k)] - m[k]*m[k];
    a0[k] = g0[k]*rsqrtf(var + EPSBN);
    c0[k] = b0[k] - m[k]*a0[k];
  }
  if (t < 9){ ac0[t] = a0[t]; ac0[9+t] = c0[t]; }
  float wj[9];
  #pragma unroll
  for (int k=0;k<9;k++) wj[k] = w1[(size_t)k*64 + t];
  float mean = 0.f;
  #pragma unroll
  for (int k=0;k<9;k++) mean += (m[k]*a0[k] + c0[k])*wj[k];
  float e2 = 0.f;
  #pragma unroll
  for (int k=0;k<9;k++)
    #pragma unroll
    for (int l=0;l<9;l++){
      float U = a0[k]*a0[l]*qb[tri(k,l)] + a0[k]*c0[l]*m[k] + a0[l]*c0[k]*m[l] + c0[k]*c0[l];
      e2 += wj[k]*wj[l]*U;
    }
  float var = e2 - mean*mean;
  float a = g1[t]*rsqrtf(var + EPSBN);
  ac1[t] = a;
  ac1[64+t] = b1[t] - mean*a;
}

// reduce slices -> a = g*rsqrt(var+eps), c = b - mean*a.  Stats over RAW
// (bias-free) pre-BN activations; linear bias cancels in training-mode BN.
__global__ void k_fin(const float* __restrict__ slices, int M, float invN,
    const float* __restrict__ g, const float* __restrict__ b, float* __restrict__ ac){
  int j = blockIdx.x*64 + threadIdx.x;
  if (j >= M) return;
  float s = 0.f, ss = 0.f;
  for (int sl = 0; sl < SLICES; sl++){
    s  += slices[(size_t)sl*2*M + j];
    ss += slices[(size_t)sl*2*M + M + j];
  }
  float mean = s*invN;
  float var = ss*invN - mean*mean;
  float a = g[j]*rsqrtf(var + EPSBN);
  ac[j] = a;
  ac[M+j] = b[j] - mean*a;
}

// ---------------- fused MFMA recompute chain, barrier-free weight streaming ----------------
// 64 rows/block, 4 waves. DEPTH=2: t2 stats. DEPTH=3: t3 stats.
// DEPTH=4: rows gathered via csr; dense y4 store in CSR order.
template<int DEPTH>
__global__ __launch_bounds__(256,2) void k_chain(
    const float* __restrict__ feats, const float* __restrict__ ac0,
    const ushort* __restrict__ w1f, const float* __restrict__ ac1,
    const ushort* __restrict__ w2f, const float* __restrict__ ac2,
    const ushort* __restrict__ w3f, const float* __restrict__ ac3,
    const ushort* __restrict__ w4f, const float* __restrict__ b4,
    const unsigned* __restrict__ csr, ushort* __restrict__ y4,
    float* __restrict__ slices, int n){
  constexpr int SMEM = (DEPTH==2) ? 12288 : (DEPTH==3) ? 28672 : 32768;
  __shared__ __align__(16) char smem[SMEM];
  __shared__ unsigned rid_s[64];
  char* X0 = smem;                  // [64][32]  bf16 swz<32>,  4KB

  int t = threadIdx.x;
  int lane = t & 63, w = t >> 6;
  int lrow = lane & 15, lgrp = lane >> 4;
  int rowbase = blockIdx.x * 64;

  // stage-1 B-frag (issued before staging; overlaps)
  bf16x8 b1 = *(const bf16x8*)(w1f + (size_t)(w*64 + lane)*8);

  if constexpr (DEPTH == 4){
    if (t < 64){
      int gr = rowbase + t;
      rid_s[t] = (gr < n) ? csr[gr] : 0u;
    }
    __syncthreads();
  }

  // ---- X0 = bn0(feats), K padded to 32, rows >= n zeroed ----
  for (int e = t; e < 2048; e += 256){
    int row = e >> 5, k = e & 31;
    int gr = rowbase + row;
    size_t rid = (DEPTH == 4) ? (size_t)rid_s[row] : (size_t)gr;
    float v = (k < 9 && gr < n) ? fmaf(feats[rid*9 + k], ac0[k], ac0[9+k]) : 0.f;
    *(ushort*)(X0 + swz<32>(row, k*2)) = f2bf(v);
  }
  __syncthreads();

  // ---- stage 1: t1 = X0 @ w1 (wave w: cols 16w..16w+16) ----
  f32x4 acc0[4] = {};
  #pragma unroll
  for (int rb = 0; rb < 4; rb++){
    bf16x8 a = *(const bf16x8*)(X0 + swz<32>(rb*16 + lrow, lgrp*16));
    acc0[rb] = __builtin_amdgcn_mfma_f32_16x16x32_bf16(a, b1, acc0[rb], 0,0,0);
  }

  char* T1 = smem + 4096;           // [64][64] bf16 swz<64>, 8KB
  // ---- T1 = bf16(relu(bn1(t1))), rows >= n zeroed ----
  {
    int j = w*16 + lrow;
    float a1 = ac1[j], c1 = ac1[64+j];
    #pragma unroll
    for (int rb=0;rb<4;rb++)
      #pragma unroll
      for (int r=0;r<4;r++){
        int row = rb*16 + 4*lgrp + r;
        float v = fmaxf(fmaf(acc0[rb][r], a1, c1), 0.f);
        if (rowbase + row >= n) v = 0.f;
        *(ushort*)(T1 + swz<64>(row, j*2)) = f2bf(v);
      }
  }
  __syncthreads();

  // ---- stage 2: 64x64 @ 64x128 (wave w: cols 32w..32w+32) ----
  f32x4 acc1[4][2] = {};
  #pragma unroll
  for (int ks=0; ks<2; ks++){
    bf16x8 bb[2];
    #pragma unroll
    for (int f=0;f<2;f++)
      bb[f] = *(const bf16x8*)(w2f + (size_t)((ks*8 + 2*w + f)*64 + lane)*8);
    #pragma unroll
    for (int rb=0;rb<4;rb++){
      bf16x8 a = *(const bf16x8*)(T1 + swz<64>(rb*16 + lrow, ks*64 + lgrp*16));
      #pragma unroll
      for (int f=0;f<2;f++)
        acc1[rb][f] = __builtin_amdgcn_mfma_f32_16x16x32_bf16(a, bb[f], acc1[rb][f], 0,0,0);
    }
  }

  if constexpr (DEPTH == 2){
    float s[2]={0.f,0.f}, ss[2]={0.f,0.f};
    #pragma unroll
    for (int rb=0;rb<4;rb++)
      #pragma unroll
      for (int f=0;f<2;f++)
        #pragma unroll
        for (int r=0;r<4;r++){ float v=acc1[rb][f][r]; s[f]+=v; ss[f]+=v*v; }
    __syncthreads();
    float* ssum = (float*)smem;
    ssum[t] = 0.f;
    __syncthreads();
    #pragma unroll
    for (int f=0;f<2;f++){
      int j = w*32 + 16*f + lrow;
      atomicAdd(&ssum[j], s[f]); atomicAdd(&ssum[128+j], ss[f]);
    }
    __syncthreads();
    float* gsl = slices + (size_t)(blockIdx.x & (SLICES-1))*256;
    atomicAdd(&gsl[t], ssum[t]);
    return;
  }

  if constexpr (DEPTH >= 3){
  char* T2 = smem + 12288;          // [64][128] bf16 swz<128>, 16KB
  // ---- T2 = bf16(relu(bn2(t2))), rows >= n zeroed ----
  #pragma unroll
  for (int f=0;f<2;f++){
    int j = w*32 + 16*f + lrow;
    float a2 = ac2[j], c2 = ac2[128+j];
    #pragma unroll
    for (int rb=0;rb<4;rb++)
      #pragma unroll
      for (int r=0;r<4;r++){
        int row = rb*16 + 4*lgrp + r;
        float v = fmaxf(fmaf(acc1[rb][f][r], a2, c2), 0.f);
        if (rowbase + row >= n) v = 0.f;
        *(ushort*)(T2 + swz<128>(row, j*2)) = f2bf(v);
      }
  }
  __syncthreads();

  if constexpr (DEPTH == 3){
    // ---- stage 3 (stats only): two 32-col halves to cap VGPR ----
    float s3[2][2], ss3[2][2];
    #pragma unroll
    for (int h=0; h<2; h++){
      f32x4 acc2[4][2] = {};
      #pragma unroll
      for (int ks=0; ks<4; ks++){
        bf16x8 bb[2];
        #pragma unroll
        for (int f=0;f<2;f++)
          bb[f] = *(const bf16x8*)(w3f + (size_t)((ks*16 + 4*w + 2*h + f)*64 + lane)*8);
        #pragma unroll
        for (int rb=0;rb<4;rb++){
          bf16x8 a = *(const bf16x8*)(T2 + swz<128>(rb*16 + lrow, ks*64 + lgrp*16));
          #pragma unroll
          for (int f=0;f<2;f++)
            acc2[rb][f] = __builtin_amdgcn_mfma_f32_16x16x32_bf16(a, bb[f], acc2[rb][f], 0,0,0);
        }
      }
      #pragma unroll
      for (int f=0;f<2;f++){
        float s=0.f, ss=0.f;
        #pragma unroll
        for (int rb=0;rb<4;rb++)
          #pragma unroll
          for (int r=0;r<4;r++){ float v=acc2[rb][f][r]; s+=v; ss+=v*v; }
        s3[h][f]=s; ss3[h][f]=ss;
      }
    }
    __syncthreads();
    float* ssum = (float*)smem;
    for (int e=t; e<512; e+=256) ssum[e] = 0.f;
    __syncthreads();
    #pragma unroll
    for (int h=0;h<2;h++)
      #pragma unroll
      for (int f=0;f<2;f++){
        int j = 64*w + 32*h + 16*f + lrow;
        atomicAdd(&ssum[j], s3[h][f]); atomicAdd(&ssum[256+j], ss3[h][f]);
      }
    __syncthreads();
    float* gsl = slices + (size_t)(blockIdx.x & (SLICES-1))*512;
    for (int e=t; e<512; e+=256) atomicAdd(&gsl[e], ssum[e]);
    return;
  }

  if constexpr (DEPTH == 4){
  // ---- stage 3 full into registers: wave w owns cols 64w..64w+64 ----
  f32x4 acc2[4][4] = {};
  #pragma unroll
  for (int ks=0; ks<4; ks++){
    bf16x8 bb[4];
    #pragma unroll
    for (int f=0;f<4;f++)
      bb[f] = *(const bf16x8*)(w3f + (size_t)((ks*16 + 4*w + f)*64 + lane)*8);
    #pragma unroll
    for (int rb=0;rb<4;rb++){
      bf16x8 a = *(const bf16x8*)(T2 + swz<128>(rb*16 + lrow, ks*64 + lgrp*16));
      #pragma unroll
      for (int f=0;f<4;f++)
        acc2[rb][f] = __builtin_amdgcn_mfma_f32_16x16x32_bf16(a, bb[f], acc2[rb][f], 0,0,0);
    }
  }
  __syncthreads();   // T2 (and X0/T1) dead -> X3 aliases smem base

  // ---- X3 = bf16(relu(bn3(t3))) at smem+0, [64][256] swz<256>, 32KB ----
  char* X3 = smem;
  #pragma unroll
  for (int f=0;f<4;f++){
    int j = 64*w + 16*f + lrow;
    float a3 = ac3[j], c3 = ac3[256+j];
    #pragma unroll
    for (int rb=0;rb<4;rb++)
      #pragma unroll
      for (int r=0;r<4;r++){
        int row = rb*16 + 4*lgrp + r;
        float v = fmaxf(fmaf(acc2[rb][f][r], a3, c3), 0.f);
        if (rowbase + row >= n) v = 0.f;
        *(ushort*)(X3 + swz<256>(row, j*2)) = f2bf(v);
      }
  }
  __syncthreads();

  // ---- stage 4: 64x256 @ 256x64 (wave w: cols 16w..16w+16) ----
  f32x4 acc3[4] = {};
  #pragma unroll
  for (int ks=0; ks<8; ks++){
    bf16x8 b = *(const bf16x8*)(w4f + (size_t)((ks*4 + w)*64 + lane)*8);
    #pragma unroll
    for (int rb=0;rb<4;rb++){
      bf16x8 a = *(const bf16x8*)(X3 + swz<256>(rb*16 + lrow, ks*64 + lgrp*16));
      acc3[rb] = __builtin_amdgcn_mfma_f32_16x16x32_bf16(a, b, acc3[rb], 0,0,0);
    }
  }

  // ---- dense store (CSR order): y4[gr][j] = t4 + b4 ----
  {
    int j = w*16 + lrow;
    float bias4 = b4[j];
    #pragma unroll
    for (int rb=0;rb<4;rb++)
      #pragma unroll
      for (int r=0;r<4;r++){
        int gr = rowbase + 16*rb + 4*lgrp + r;
        if (gr < n) y4[(size_t)gr*64 + j] = f2bf(acc3[rb][r] + bias4);
      }
  }
  } // DEPTH==4
  } // DEPTH>=3
}

// ---------------- pool (contiguous segment max) + projection + unq padding ----------------
// 4 waves/block, one output row per wave. Lane = (p, c8): p = lane>>3 point slot,
// c8 = lane&7 channel-octet. All <=8 points fetched in one parallel round.
__global__ __launch_bounds__(256) void k_pool(const ushort* __restrict__ y4,
    const unsigned* __restrict__ vst, const unsigned* __restrict__ vct,
    const unsigned* __restrict__ boff, const float* __restrict__ wp,
    const float* __restrict__ bp, float* __restrict__ out,
    float* __restrict__ unq, int n){
  __shared__ float wps[1024];       // wp [64][16]
  __shared__ float sm[4][64];
  int t = threadIdx.x, w = t >> 6, lane = t & 63;
  for (int e=t; e<1024; e+=256) wps[e] = wp[e];
  int r = blockIdx.x*4 + w;
  unsigned M = boff[216];
  int c8 = lane & 7, p = lane >> 3;
  if (r < n){
    float m8[8];
    if (r < (int)M){
      unsigned st = vst[r], c = vct[r];
      #pragma unroll
      for (int i=0;i<8;i++) m8[i] = -3.0e38f;
      for (unsigned p0 = 0; p0 < c; p0 += 8){
        unsigned pp = p0 + (unsigned)p;
        if (pp < c){
          bf16x8 v = *(const bf16x8*)(y4 + ((size_t)st + pp)*64 + c8*8);
          #pragma unroll
          for (int i=0;i<8;i++) m8[i] = fmaxf(m8[i], bf2f((ushort)v[i]));
        }
      }
      #pragma unroll
      for (int mask=8; mask<64; mask<<=1)
        #pragma unroll
        for (int i=0;i<8;i++) m8[i] = fmaxf(m8[i], __shfl_xor(m8[i], mask, 64));
    } else {
      #pragma unroll
      for (int i=0;i<8;i++) m8[i] = 0.f;           // padding voxel: pooled = 0
      if (lane < 3) unq[3*(size_t)r + lane] = -1.f; // unq padding (was k_pad)
    }
    if (p == 0){
      #pragma unroll
      for (int i=0;i<8;i++) sm[w][c8*8 + i] = m8[i];
    }
  }
  __syncthreads();
  if (r < n){
    int q = lane >> 4, j = lane & 15;
    float acc = 0.f;
    #pragma unroll
    for (int i=0;i<16;i++) acc = fmaf(sm[w][q*16+i], wps[(q*16+i)*16 + j], acc);
    acc += __shfl_xor(acc, 16, 64);
    acc += __shfl_xor(acc, 32, 64);
    if (lane < 16) out[(size_t)r*16 + lane] = fmaxf(acc + bp[lane], 0.f);
  }
}

extern "C" void kernel_launch(void* const* d_in, const int* in_sizes, int n_in,
                              void* d_out, int out_size, void* d_ws, size_t ws_size,
                              hipStream_t stream){
  (void)n_in; (void)out_size;
  const float* feats  = (const float*)d_in[0];
  const int*   coords = (const int*)d_in[1];
  const float* g0=(const float*)d_in[2];  const float* bb0=(const float*)d_in[3];
  const float* g1=(const float*)d_in[4];  const float* bb1=(const float*)d_in[5];
  const float* g2=(const float*)d_in[6];  const float* bb2=(const float*)d_in[7];
  const float* g3=(const float*)d_in[8];  const float* bb3=(const float*)d_in[9];
  const float* w1=(const float*)d_in[10];
  const float* w2=(const float*)d_in[12];
  const float* w3=(const float*)d_in[14];
  const float* w4=(const float*)d_in[16]; const float* b4=(const float*)d_in[17];
  const float* wp=(const float*)d_in[18]; const float* bp=(const float*)d_in[19];
  int n = in_sizes[0]/9;

  char* ws = (char*)d_ws;
  size_t off = 0;
  auto alloc = [&](size_t bytes){ size_t o = off; off = (off + bytes + 255) & ~(size_t)255; return o; };
  size_t o_cnt  = alloc((size_t)NKEYS*4);            // zeroed
  size_t o_cur  = alloc((size_t)NKEYS*4);            // zeroed (csr cursors)
  size_t o_sl0  = alloc((size_t)SLICES*54*4);        // zeroed
  size_t o_sl2  = alloc((size_t)SLICES*256*4);       // zeroed
  size_t o_sl3  = alloc((size_t)SLICES*512*4);       // zeroed
  size_t zero_end = off;
  size_t o_rloc = alloc((size_t)NKEYS*4);
  size_t o_ploc = alloc((size_t)NKEYS*4);
  size_t o_bsum = alloc(256*4);
  size_t o_boff = alloc(256*4);
  size_t o_ac0  = alloc(18*4);
  size_t o_ac1  = alloc(128*4);
  size_t o_ac2  = alloc(256*4);
  size_t o_ac3  = alloc(512*4);
  size_t o_w1f  = alloc(2048*2);
  size_t o_w2f  = alloc(8192*2);
  size_t o_w3f  = alloc(32768*2);
  size_t o_w4f  = alloc(16384*2);
  size_t o_csr  = alloc((size_t)n*4);
  size_t o_vst  = alloc((size_t)n*4);
  size_t o_vct  = alloc((size_t)n*4);
  size_t o_y4   = alloc((size_t)n*64*2);
  if (ws_size < off) return;                         // clean fail if ws too small

  unsigned* cnt  = (unsigned*)(ws + o_cnt);
  unsigned* cursor = (unsigned*)(ws + o_cur);
  unsigned* rloc = (unsigned*)(ws + o_rloc);
  unsigned* ploc = (unsigned*)(ws + o_ploc);
  unsigned* bsum = (unsigned*)(ws + o_bsum);
  unsigned* boff = (unsigned*)(ws + o_boff);
  float* sl0 = (float*)(ws + o_sl0);
  float* sl2 = (float*)(ws + o_sl2);
  float* sl3 = (float*)(ws + o_sl3);
  float* ac0 = (float*)(ws + o_ac0);
  float* ac1 = (float*)(ws + o_ac1);
  float* ac2 = (float*)(ws + o_ac2);
  float* ac3 = (float*)(ws + o_ac3);
  ushort* w1f = (ushort*)(ws + o_w1f);
  ushort* w2f = (ushort*)(ws + o_w2f);
  ushort* w3f = (ushort*)(ws + o_w3f);
  ushort* w4f = (ushort*)(ws + o_w4f);
  unsigned* csr = (unsigned*)(ws + o_csr);
  unsigned* vst = (unsigned*)(ws + o_vst);
  unsigned* vct = (unsigned*)(ws + o_vct);
  ushort* y4 = (ushort*)(ws + o_y4);

  float* out_pool = (float*)d_out;
  float* out_unq  = out_pool + (size_t)n*16;

  {
    size_t n16 = zero_end/16;
    int zb = (int)((n16 + 255)/256); if (zb > 2048) zb = 2048;
    k_zero<<<zb,256,0,stream>>>((uint4*)ws, n16);
  }

  // weight prep (bf16, B-fragment order)
  k_wprep<<<8,256,0,stream>>>(w1, w1f, 9, 64);
  k_wprep<<<32,256,0,stream>>>(w2, w2f, 64, 128);
  k_wprep<<<128,256,0,stream>>>(w3, w3f, 128, 256);
  k_wprep<<<64,256,0,stream>>>(w4, w4f, 256, 64);

  int nb = (n + 255)/256;
  k_keys<<<nb,256,0,stream>>>(coords, cnt, n);
  k_scan1<<<NKEYS/1024,256,0,stream>>>(cnt, rloc, ploc, bsum);
  k_scan2<<<1,128,0,stream>>>(bsum, boff);
  k_unq<<<(NKEYS+255)/256,256,0,stream>>>(cnt, rloc, ploc, boff, out_unq, vst, vct);
  k_csr<<<nb,256,0,stream>>>(coords, ploc, boff, cursor, csr, n);

  // feats moments -> ac0 + analytic ac1
  k_stats0x<<<512,256,0,stream>>>(feats, sl0, n);
  k_fin01<<<1,64,0,stream>>>(sl0, 1.f/(float)n, g0, bb0, g1, bb1, w1, ac0, ac1);

  int gb = (n+63)/64;
  k_chain<2><<<gb,256,0,stream>>>(feats, ac0, w1f, ac1, w2f, ac2, w3f, ac3, w4f, b4, nullptr, nullptr, sl2, n);
  k_fin<<<2,64,0,stream>>>(sl2, 128, 1.f/(float)n, g2, bb2, ac2);

  k_chain<3><<<gb,256,0,stream>>>(feats, ac0, w1f, ac1, w2f, ac2, w3f, ac3, w4f, b4, nullptr, nullptr, sl3, n);
  k_fin<<<4,64,0,stream>>>(sl3, 256, 1.f/(float)n, g3, bb3, ac3);

  k_chain<4><<<gb,256,0,stream>>>(feats, ac0, w1f, ac1, w2f, ac2, w3f, ac3, w4f, b4, csr, y4, nullptr, n);

  k_pool<<<(n+3)/4,256,0,stream>>>(y4, vst, vct, boff, wp, bp, out_pool, out_unq, n);
}

// Round 9
// 318.744 us; speedup vs baseline: 1.2014x; 1.1486x over previous
//
#include <hip/hip_runtime.h>
#include <hip/hip_bf16.h>

#define EPSBN 1e-5f
#define NKEYS 110592   // 48^3
#define SLICES 64
#define VPW 8          // voxels per wave in k_pool

typedef __attribute__((ext_vector_type(8))) short bf16x8;
typedef __attribute__((ext_vector_type(4))) float f32x4;

__device__ __forceinline__ float bf2f(ushort u){ return __uint_as_float(((unsigned)u)<<16); }
__device__ __forceinline__ ushort f2bf(float f){
  unsigned u = __float_as_uint(f);
  unsigned r = u + 0x7fffu + ((u>>16)&1u);
  return (ushort)(r>>16);
}

// XOR-swizzled byte offset in row-major [R][KP] bf16 tile (bank-conflict fix).
template<int KP>
__device__ __forceinline__ int swz(int row, int kbyte){
  constexpr int MASK = (KP >= 64) ? 7 : 3;
  return row*(KP*2) + (kbyte ^ ((row & MASK) << 4));
}

__device__ __forceinline__ int tri(int k, int l){
  if (k > l){ int t=k; k=l; l=t; }
  return k*9 - (k*(k-1))/2 + (l-k);
}

// ---------------- zero scratch ----------------
__global__ __launch_bounds__(256) void k_zero(uint4* __restrict__ p, size_t n16){
  size_t i = (size_t)blockIdx.x*256 + threadIdx.x;
  size_t stride = (size_t)gridDim.x*256;
  uint4 z = make_uint4(0,0,0,0);
  for (; i < n16; i += stride) p[i] = z;
}

// ---------------- weight prep: f32 [K][M] -> B-fragment order ----------------
__global__ __launch_bounds__(256) void k_wprep(const float* __restrict__ w,
    ushort* __restrict__ wf, int K, int M){
  int CT = M >> 4;
  int KS = (K + 31) >> 5;
  int total = KS*CT*512;
  for (int idx = blockIdx.x*256 + threadIdx.x; idx < total; idx += gridDim.x*256){
    int e = idx & 7, l = (idx>>3) & 63, c = idx >> 9;
    int ct = c % CT, ks = c / CT;
    int g = l >> 4, j = l & 15;
    int k = ks*32 + g*8 + e, col = ct*16 + j;
    wf[idx] = (k < K) ? f2bf(w[(size_t)k*M + col]) : (ushort)0;
  }
}

// ---------------- voxel unique ----------------
__global__ __launch_bounds__(256) void k_keys(const int* __restrict__ coords,
    unsigned* __restrict__ cnt, int n){
  int i = blockIdx.x*256 + threadIdx.x;
  if (i >= n) return;
  int x = coords[3*i+0], y = coords[3*i+1], z = coords[3*i+2];
  atomicAdd(&cnt[(unsigned)((x*48 + y)*48 + z)], 1u);
}

// pair-scan: flags (occupancy) AND counts, per 1024-key chunk
__global__ __launch_bounds__(256) void k_scan1(const unsigned* __restrict__ cnt,
    unsigned* __restrict__ rloc, unsigned* __restrict__ ploc, unsigned* __restrict__ bsum){
  __shared__ unsigned tf[256], tc[256];
  int t = threadIdx.x;
  int base = blockIdx.x*1024 + t*4;
  uint4 cv = *(const uint4*)&cnt[base];
  unsigned f0 = cv.x?1u:0u, f1 = cv.y?1u:0u, f2 = cv.z?1u:0u, f3 = cv.w?1u:0u;
  unsigned sf = f0+f1+f2+f3;
  unsigned sc = cv.x+cv.y+cv.z+cv.w;
  tf[t] = sf; tc[t] = sc;
  __syncthreads();
  for (int off=1; off<256; off<<=1){
    unsigned af = (t>=off) ? tf[t-off] : 0u;
    unsigned ac = (t>=off) ? tc[t-off] : 0u;
    __syncthreads();
    tf[t] += af; tc[t] += ac;
    __syncthreads();
  }
  unsigned rf = tf[t] - sf, rc = tc[t] - sc;
  rloc[base+0] = rf; rf += f0;    ploc[base+0] = rc; rc += cv.x;
  rloc[base+1] = rf; rf += f1;    ploc[base+1] = rc; rc += cv.y;
  rloc[base+2] = rf; rf += f2;    ploc[base+2] = rc; rc += cv.z;
  rloc[base+3] = rf;              ploc[base+3] = rc;
  if (t == 255){ bsum[2*blockIdx.x] = tf[255]; bsum[2*blockIdx.x+1] = tc[255]; }
}

__global__ __launch_bounds__(128) void k_scan2(const unsigned* __restrict__ bsum,
    unsigned* __restrict__ boff){
  __shared__ unsigned tf[128], tc[128];
  int t = threadIdx.x;
  unsigned vf = (t < 108) ? bsum[2*t] : 0u;
  unsigned vc = (t < 108) ? bsum[2*t+1] : 0u;
  tf[t] = vf; tc[t] = vc;
  __syncthreads();
  for (int off=1; off<128; off<<=1){
    unsigned af = (t>=off) ? tf[t-off] : 0u;
    unsigned ac = (t>=off) ? tc[t-off] : 0u;
    __syncthreads();
    tf[t] += af; tc[t] += ac;
    __syncthreads();
  }
  boff[2*t] = tf[t] - vf;     // flag-offset; boff[216] = total M
  boff[2*t+1] = tc[t] - vc;   // count-offset
}

// unique rows + per-voxel CSR geometry (start, count)
__global__ __launch_bounds__(256) void k_unq(const unsigned* __restrict__ cnt,
    const unsigned* __restrict__ rloc, const unsigned* __restrict__ ploc,
    const unsigned* __restrict__ boff, float* __restrict__ unq,
    unsigned* __restrict__ vst, unsigned* __restrict__ vct){
  int k = blockIdx.x*256 + threadIdx.x;
  if (k >= NKEYS) return;
  unsigned c = cnt[k];
  if (c == 0) return;
  unsigned r  = rloc[k] + boff[2*(k>>10)];
  unsigned st = ploc[k] + boff[2*(k>>10)+1];
  float z = (float)(k % 48);
  float y = (float)((k/48) % 48);
  float x = (float)(k / 2304);
  unq[3*(size_t)r+0] = x; unq[3*(size_t)r+1] = y; unq[3*(size_t)r+2] = z;
  vst[r] = st; vct[r] = c;
}

// place each point into its voxel's CSR slot
__global__ __launch_bounds__(256) void k_csr(const int* __restrict__ coords,
    const unsigned* __restrict__ ploc, const unsigned* __restrict__ boff,
    unsigned* __restrict__ cursor, unsigned* __restrict__ csr, int n){
  int i = blockIdx.x*256 + threadIdx.x;
  if (i >= n) return;
  int x = coords[3*i+0], y = coords[3*i+1], z = coords[3*i+2];
  unsigned k = (unsigned)((x*48 + y)*48 + z);
  unsigned slot = atomicAdd(&cursor[k], 1u);
  unsigned st = ploc[k] + boff[2*(k>>10)+1];
  csr[st + slot] = i;
}

// ---------------- feats moments: s[9] = sum x, q[45] = sum x_k x_l (k<=l) ----------------
__global__ __launch_bounds__(256) void k_stats0x(const float* __restrict__ X,
    float* __restrict__ slices, int n){
  float s[9], q[45];
  #pragma unroll
  for (int k=0;k<9;k++) s[k]=0.f;
  #pragma unroll
  for (int i=0;i<45;i++) q[i]=0.f;
  int stride = gridDim.x*256;
  for (int i = blockIdx.x*256 + threadIdx.x; i < n; i += stride){
    float v[9];
    #pragma unroll
    for (int k=0;k<9;k++) v[k] = X[(size_t)i*9+k];
    int qi=0;
    #pragma unroll
    for (int k=0;k<9;k++){
      s[k] += v[k];
      #pragma unroll
      for (int l=k;l<9;l++) q[qi++] += v[k]*v[l];
    }
  }
  #pragma unroll
  for (int off=32; off>0; off>>=1){
    #pragma unroll
    for (int k=0;k<9;k++)  s[k] += __shfl_down(s[k], off, 64);
    #pragma unroll
    for (int i=0;i<45;i++) q[i] += __shfl_down(q[i], off, 64);
  }
  if ((threadIdx.x & 63) == 0){
    float* sl = slices + (size_t)(blockIdx.x & (SLICES-1))*54;
    #pragma unroll
    for (int k=0;k<9;k++)  atomicAdd(&sl[k],   s[k]);
    #pragma unroll
    for (int i=0;i<45;i++) atomicAdd(&sl[9+i], q[i]);
  }
}

// ---------------- ac0 + analytic ac1 from feats moments ----------------
__global__ void k_fin01(const float* __restrict__ slices, float invN,
    const float* __restrict__ g0, const float* __restrict__ b0,
    const float* __restrict__ g1, const float* __restrict__ b1,
    const float* __restrict__ w1, float* __restrict__ ac0, float* __restrict__ ac1){
  __shared__ float red[54];
  int t = threadIdx.x;   // 64 threads
  if (t < 54){
    float a = 0.f;
    for (int sl=0; sl<SLICES; sl++) a += slices[(size_t)sl*54 + t];
    red[t] = a;
  }
  __syncthreads();
  float m[9], a0[9], c0[9], qb[45];
  #pragma unroll
  for (int k=0;k<9;k++) m[k] = red[k]*invN;
  #pragma unroll
  for (int i=0;i<45;i++) qb[i] = red[9+i]*invN;
  #pragma unroll
  for (int k=0;k<9;k++){
    float var = qb[tri(k,k)] - m[k]*m[k];
    a0[k] = g0[k]*rsqrtf(var + EPSBN);
    c0[k] = b0[k] - m[k]*a0[k];
  }
  if (t < 9){ ac0[t] = a0[t]; ac0[9+t] = c0[t]; }
  float wj[9];
  #pragma unroll
  for (int k=0;k<9;k++) wj[k] = w1[(size_t)k*64 + t];
  float mean = 0.f;
  #pragma unroll
  for (int k=0;k<9;k++) mean += (m[k]*a0[k] + c0[k])*wj[k];
  float e2 = 0.f;
  #pragma unroll
  for (int k=0;k<9;k++)
    #pragma unroll
    for (int l=0;l<9;l++){
      float U = a0[k]*a0[l]*qb[tri(k,l)] + a0[k]*c0[l]*m[k] + a0[l]*c0[k]*m[l] + c0[k]*c0[l];
      e2 += wj[k]*wj[l]*U;
    }
  float var = e2 - mean*mean;
  float a = g1[t]*rsqrtf(var + EPSBN);
  ac1[t] = a;
  ac1[64+t] = b1[t] - mean*a;
}

// reduce slices -> a = g*rsqrt(var+eps), c = b - mean*a.  Stats over RAW
// (bias-free) pre-BN activations; linear bias cancels in training-mode BN.
__global__ void k_fin(const float* __restrict__ slices, int M, float invN,
    const float* __restrict__ g, const float* __restrict__ b, float* __restrict__ ac){
  int j = blockIdx.x*64 + threadIdx.x;
  if (j >= M) return;
  float s = 0.f, ss = 0.f;
  for (int sl = 0; sl < SLICES; sl++){
    s  += slices[(size_t)sl*2*M + j];
    ss += slices[(size_t)sl*2*M + M + j];
  }
  float mean = s*invN;
  float var = ss*invN - mean*mean;
  float a = g[j]*rsqrtf(var + EPSBN);
  ac[j] = a;
  ac[M+j] = b[j] - mean*a;
}

// ---------------- fused MFMA recompute chain, barrier-free weight streaming ----------------
// 64 rows/block, 4 waves. DEPTH=2: t2 stats. DEPTH=3: t3 stats.
// DEPTH=4: rows gathered via csr; dense y4 store in CSR order.
template<int DEPTH>
__global__ __launch_bounds__(256,2) void k_chain(
    const float* __restrict__ feats, const float* __restrict__ ac0,
    const ushort* __restrict__ w1f, const float* __restrict__ ac1,
    const ushort* __restrict__ w2f, const float* __restrict__ ac2,
    const ushort* __restrict__ w3f, const float* __restrict__ ac3,
    const ushort* __restrict__ w4f, const float* __restrict__ b4,
    const unsigned* __restrict__ csr, ushort* __restrict__ y4,
    float* __restrict__ slices, int n){
  constexpr int SMEM = (DEPTH==2) ? 12288 : (DEPTH==3) ? 28672 : 32768;
  __shared__ __align__(16) char smem[SMEM];
  __shared__ unsigned rid_s[64];
  char* X0 = smem;                  // [64][32]  bf16 swz<32>,  4KB

  int t = threadIdx.x;
  int lane = t & 63, w = t >> 6;
  int lrow = lane & 15, lgrp = lane >> 4;
  int rowbase = blockIdx.x * 64;

  // stage-1 B-frag (issued before staging; overlaps)
  bf16x8 b1 = *(const bf16x8*)(w1f + (size_t)(w*64 + lane)*8);

  if constexpr (DEPTH == 4){
    if (t < 64){
      int gr = rowbase + t;
      rid_s[t] = (gr < n) ? csr[gr] : 0u;
    }
    __syncthreads();
  }

  // ---- X0 = bn0(feats), K padded to 32, rows >= n zeroed ----
  for (int e = t; e < 2048; e += 256){
    int row = e >> 5, k = e & 31;
    int gr = rowbase + row;
    size_t rid = (DEPTH == 4) ? (size_t)rid_s[row] : (size_t)gr;
    float v = (k < 9 && gr < n) ? fmaf(feats[rid*9 + k], ac0[k], ac0[9+k]) : 0.f;
    *(ushort*)(X0 + swz<32>(row, k*2)) = f2bf(v);
  }
  __syncthreads();

  // ---- stage 1: t1 = X0 @ w1 (wave w: cols 16w..16w+16) ----
  f32x4 acc0[4] = {};
  #pragma unroll
  for (int rb = 0; rb < 4; rb++){
    bf16x8 a = *(const bf16x8*)(X0 + swz<32>(rb*16 + lrow, lgrp*16));
    acc0[rb] = __builtin_amdgcn_mfma_f32_16x16x32_bf16(a, b1, acc0[rb], 0,0,0);
  }

  char* T1 = smem + 4096;           // [64][64] bf16 swz<64>, 8KB
  // ---- T1 = bf16(relu(bn1(t1))), rows >= n zeroed ----
  {
    int j = w*16 + lrow;
    float a1 = ac1[j], c1 = ac1[64+j];
    #pragma unroll
    for (int rb=0;rb<4;rb++)
      #pragma unroll
      for (int r=0;r<4;r++){
        int row = rb*16 + 4*lgrp + r;
        float v = fmaxf(fmaf(acc0[rb][r], a1, c1), 0.f);
        if (rowbase + row >= n) v = 0.f;
        *(ushort*)(T1 + swz<64>(row, j*2)) = f2bf(v);
      }
  }
  __syncthreads();

  // ---- stage 2: 64x64 @ 64x128 (wave w: cols 32w..32w+32) ----
  f32x4 acc1[4][2] = {};
  #pragma unroll
  for (int ks=0; ks<2; ks++){
    bf16x8 bb[2];
    #pragma unroll
    for (int f=0;f<2;f++)
      bb[f] = *(const bf16x8*)(w2f + (size_t)((ks*8 + 2*w + f)*64 + lane)*8);
    #pragma unroll
    for (int rb=0;rb<4;rb++){
      bf16x8 a = *(const bf16x8*)(T1 + swz<64>(rb*16 + lrow, ks*64 + lgrp*16));
      #pragma unroll
      for (int f=0;f<2;f++)
        acc1[rb][f] = __builtin_amdgcn_mfma_f32_16x16x32_bf16(a, bb[f], acc1[rb][f], 0,0,0);
    }
  }

  if constexpr (DEPTH == 2){
    float s[2]={0.f,0.f}, ss[2]={0.f,0.f};
    #pragma unroll
    for (int rb=0;rb<4;rb++)
      #pragma unroll
      for (int f=0;f<2;f++)
        #pragma unroll
        for (int r=0;r<4;r++){ float v=acc1[rb][f][r]; s[f]+=v; ss[f]+=v*v; }
    __syncthreads();
    float* ssum = (float*)smem;
    ssum[t] = 0.f;
    __syncthreads();
    #pragma unroll
    for (int f=0;f<2;f++){
      int j = w*32 + 16*f + lrow;
      atomicAdd(&ssum[j], s[f]); atomicAdd(&ssum[128+j], ss[f]);
    }
    __syncthreads();
    float* gsl = slices + (size_t)(blockIdx.x & (SLICES-1))*256;
    atomicAdd(&gsl[t], ssum[t]);
    return;
  }

  if constexpr (DEPTH >= 3){
  char* T2 = smem + 12288;          // [64][128] bf16 swz<128>, 16KB
  // ---- T2 = bf16(relu(bn2(t2))), rows >= n zeroed ----
  #pragma unroll
  for (int f=0;f<2;f++){
    int j = w*32 + 16*f + lrow;
    float a2 = ac2[j], c2 = ac2[128+j];
    #pragma unroll
    for (int rb=0;rb<4;rb++)
      #pragma unroll
      for (int r=0;r<4;r++){
        int row = rb*16 + 4*lgrp + r;
        float v = fmaxf(fmaf(acc1[rb][f][r], a2, c2), 0.f);
        if (rowbase + row >= n) v = 0.f;
        *(ushort*)(T2 + swz<128>(row, j*2)) = f2bf(v);
      }
  }
  __syncthreads();

  if constexpr (DEPTH == 3){
    // ---- stage 3 (stats only): two 32-col halves to cap VGPR ----
    float s3[2][2], ss3[2][2];
    #pragma unroll
    for (int h=0; h<2; h++){
      f32x4 acc2[4][2] = {};
      #pragma unroll
      for (int ks=0; ks<4; ks++){
        bf16x8 bb[2];
        #pragma unroll
        for (int f=0;f<2;f++)
          bb[f] = *(const bf16x8*)(w3f + (size_t)((ks*16 + 4*w + 2*h + f)*64 + lane)*8);
        #pragma unroll
        for (int rb=0;rb<4;rb++){
          bf16x8 a = *(const bf16x8*)(T2 + swz<128>(rb*16 + lrow, ks*64 + lgrp*16));
          #pragma unroll
          for (int f=0;f<2;f++)
            acc2[rb][f] = __builtin_amdgcn_mfma_f32_16x16x32_bf16(a, bb[f], acc2[rb][f], 0,0,0);
        }
      }
      #pragma unroll
      for (int f=0;f<2;f++){
        float s=0.f, ss=0.f;
        #pragma unroll
        for (int rb=0;rb<4;rb++)
          #pragma unroll
          for (int r=0;r<4;r++){ float v=acc2[rb][f][r]; s+=v; ss+=v*v; }
        s3[h][f]=s; ss3[h][f]=ss;
      }
    }
    __syncthreads();
    float* ssum = (float*)smem;
    for (int e=t; e<512; e+=256) ssum[e] = 0.f;
    __syncthreads();
    #pragma unroll
    for (int h=0;h<2;h++)
      #pragma unroll
      for (int f=0;f<2;f++){
        int j = 64*w + 32*h + 16*f + lrow;
        atomicAdd(&ssum[j], s3[h][f]); atomicAdd(&ssum[256+j], ss3[h][f]);
      }
    __syncthreads();
    float* gsl = slices + (size_t)(blockIdx.x & (SLICES-1))*512;
    for (int e=t; e<512; e+=256) atomicAdd(&gsl[e], ssum[e]);
    return;
  }

  if constexpr (DEPTH == 4){
  // ---- stage 3 full into registers: wave w owns cols 64w..64w+64 ----
  f32x4 acc2[4][4] = {};
  #pragma unroll
  for (int ks=0; ks<4; ks++){
    bf16x8 bb[4];
    #pragma unroll
    for (int f=0;f<4;f++)
      bb[f] = *(const bf16x8*)(w3f + (size_t)((ks*16 + 4*w + f)*64 + lane)*8);
    #pragma unroll
    for (int rb=0;rb<4;rb++){
      bf16x8 a = *(const bf16x8*)(T2 + swz<128>(rb*16 + lrow, ks*64 + lgrp*16));
      #pragma unroll
      for (int f=0;f<4;f++)
        acc2[rb][f] = __builtin_amdgcn_mfma_f32_16x16x32_bf16(a, bb[f], acc2[rb][f], 0,0,0);
    }
  }
  __syncthreads();   // T2 (and X0/T1) dead -> X3 aliases smem base

  // ---- X3 = bf16(relu(bn3(t3))) at smem+0, [64][256] swz<256>, 32KB ----
  char* X3 = smem;
  #pragma unroll
  for (int f=0;f<4;f++){
    int j = 64*w + 16*f + lrow;
    float a3 = ac3[j], c3 = ac3[256+j];
    #pragma unroll
    for (int rb=0;rb<4;rb++)
      #pragma unroll
      for (int r=0;r<4;r++){
        int row = rb*16 + 4*lgrp + r;
        float v = fmaxf(fmaf(acc2[rb][f][r], a3, c3), 0.f);
        if (rowbase + row >= n) v = 0.f;
        *(ushort*)(X3 + swz<256>(row, j*2)) = f2bf(v);
      }
  }
  __syncthreads();

  // ---- stage 4: 64x256 @ 256x64 (wave w: cols 16w..16w+16) ----
  f32x4 acc3[4] = {};
  #pragma unroll
  for (int ks=0; ks<8; ks++){
    bf16x8 b = *(const bf16x8*)(w4f + (size_t)((ks*4 + w)*64 + lane)*8);
    #pragma unroll
    for (int rb=0;rb<4;rb++){
      bf16x8 a = *(const bf16x8*)(X3 + swz<256>(rb*16 + lrow, ks*64 + lgrp*16));
      acc3[rb] = __builtin_amdgcn_mfma_f32_16x16x32_bf16(a, b, acc3[rb], 0,0,0);
    }
  }

  // ---- dense store (CSR order): y4[gr][j] = t4 + b4 ----
  {
    int j = w*16 + lrow;
    float bias4 = b4[j];
    #pragma unroll
    for (int rb=0;rb<4;rb++)
      #pragma unroll
      for (int r=0;r<4;r++){
        int gr = rowbase + 16*rb + 4*lgrp + r;
        if (gr < n) y4[(size_t)gr*64 + j] = f2bf(acc3[rb][r] + bias4);
      }
  }
  } // DEPTH==4
  } // DEPTH>=3
}

// ---------------- pool: lane = channel, contiguous CSR rows, 8 voxels/wave ----------------
__global__ __launch_bounds__(256) void k_pool(const ushort* __restrict__ y4,
    const unsigned* __restrict__ vst, const unsigned* __restrict__ vct,
    const unsigned* __restrict__ boff, const float* __restrict__ wp,
    const float* __restrict__ bp, float* __restrict__ out, int n){
  __shared__ float wpsT[1024];      // [16][64]: wpsT[j*64+ch] = wp[ch][j]
  __shared__ float sm[4][64];
  int t = threadIdx.x, w = t >> 6, lane = t & 63;
  for (int e=t; e<1024; e+=256){
    int j = e >> 6, ch = e & 63;
    wpsT[e] = wp[ch*16 + j];
  }
  __syncthreads();
  unsigned M = boff[216];
  int base = blockIdx.x*(4*VPW) + w*VPW;
  if (base >= (int)M) return;
  float bpv = (lane < 16) ? bp[lane] : 0.f;
  int q = lane >> 4, j = lane & 15;
  int vend = (int)M - base; if (vend > VPW) vend = VPW;
  for (int v = 0; v < vend; v++){
    int r = base + v;
    unsigned st = vst[r], c = vct[r];
    const ushort* row = y4 + (size_t)st*64 + lane;
    float m = bf2f(row[0]);
    #pragma unroll 4
    for (unsigned pp = 1; pp < c; pp++)
      m = fmaxf(m, bf2f(row[(size_t)pp*64]));
    sm[w][lane] = m;                // wave-private: no barrier needed
    float acc = 0.f;
    #pragma unroll
    for (int i=0;i<16;i++) acc = fmaf(sm[w][q*16+i], wpsT[j*64 + q*16+i], acc);
    acc += __shfl_xor(acc, 16, 64);
    acc += __shfl_xor(acc, 32, 64);
    if (lane < 16) out[(size_t)r*16 + lane] = fmaxf(acc + bpv, 0.f);
  }
}

// ---------------- padding rows: out = relu(bp), unq = -1 ----------------
__global__ __launch_bounds__(256) void k_fill(const unsigned* __restrict__ boff,
    const float* __restrict__ bp, float* __restrict__ out,
    float* __restrict__ unq, int n){
  int r = blockIdx.x*256 + threadIdx.x;
  if (r >= n) return;
  unsigned M = boff[216];
  if ((unsigned)r < M) return;
  #pragma unroll
  for (int j=0;j<16;j++) out[(size_t)r*16 + j] = fmaxf(bp[j], 0.f);
  unq[3*(size_t)r+0] = -1.f; unq[3*(size_t)r+1] = -1.f; unq[3*(size_t)r+2] = -1.f;
}

extern "C" void kernel_launch(void* const* d_in, const int* in_sizes, int n_in,
                              void* d_out, int out_size, void* d_ws, size_t ws_size,
                              hipStream_t stream){
  (void)n_in; (void)out_size;
  const float* feats  = (const float*)d_in[0];
  const int*   coords = (const int*)d_in[1];
  const float* g0=(const float*)d_in[2];  const float* bb0=(const float*)d_in[3];
  const float* g1=(const float*)d_in[4];  const float* bb1=(const float*)d_in[5];
  const float* g2=(const float*)d_in[6];  const float* bb2=(const float*)d_in[7];
  const float* g3=(const float*)d_in[8];  const float* bb3=(const float*)d_in[9];
  const float* w1=(const float*)d_in[10];
  const float* w2=(const float*)d_in[12];
  const float* w3=(const float*)d_in[14];
  const float* w4=(const float*)d_in[16]; const float* b4=(const float*)d_in[17];
  const float* wp=(const float*)d_in[18]; const float* bp=(const float*)d_in[19];
  int n = in_sizes[0]/9;

  char* ws = (char*)d_ws;
  size_t off = 0;
  auto alloc = [&](size_t bytes){ size_t o = off; off = (off + bytes + 255) & ~(size_t)255; return o; };
  size_t o_cnt  = alloc((size_t)NKEYS*4);            // zeroed
  size_t o_cur  = alloc((size_t)NKEYS*4);            // zeroed (csr cursors)
  size_t o_sl0  = alloc((size_t)SLICES*54*4);        // zeroed
  size_t o_sl2  = alloc((size_t)SLICES*256*4);       // zeroed
  size_t o_sl3  = alloc((size_t)SLICES*512*4);       // zeroed
  size_t zero_end = off;
  size_t o_rloc = alloc((size_t)NKEYS*4);
  size_t o_ploc = alloc((size_t)NKEYS*4);
  size_t o_bsum = alloc(256*4);
  size_t o_boff = alloc(256*4);
  size_t o_ac0  = alloc(18*4);
  size_t o_ac1  = alloc(128*4);
  size_t o_ac2  = alloc(256*4);
  size_t o_ac3  = alloc(512*4);
  size_t o_w1f  = alloc(2048*2);
  size_t o_w2f  = alloc(8192*2);
  size_t o_w3f  = alloc(32768*2);
  size_t o_w4f  = alloc(16384*2);
  size_t o_csr  = alloc((size_t)n*4);
  size_t o_vst  = alloc((size_t)n*4);
  size_t o_vct  = alloc((size_t)n*4);
  size_t o_y4   = alloc((size_t)n*64*2);
  if (ws_size < off) return;                         // clean fail if ws too small

  unsigned* cnt  = (unsigned*)(ws + o_cnt);
  unsigned* cursor = (unsigned*)(ws + o_cur);
  unsigned* rloc = (unsigned*)(ws + o_rloc);
  unsigned* ploc = (unsigned*)(ws + o_ploc);
  unsigned* bsum = (unsigned*)(ws + o_bsum);
  unsigned* boff = (unsigned*)(ws + o_boff);
  float* sl0 = (float*)(ws + o_sl0);
  float* sl2 = (float*)(ws + o_sl2);
  float* sl3 = (float*)(ws + o_sl3);
  float* ac0 = (float*)(ws + o_ac0);
  float* ac1 = (float*)(ws + o_ac1);
  float* ac2 = (float*)(ws + o_ac2);
  float* ac3 = (float*)(ws + o_ac3);
  ushort* w1f = (ushort*)(ws + o_w1f);
  ushort* w2f = (ushort*)(ws + o_w2f);
  ushort* w3f = (ushort*)(ws + o_w3f);
  ushort* w4f = (ushort*)(ws + o_w4f);
  unsigned* csr = (unsigned*)(ws + o_csr);
  unsigned* vst = (unsigned*)(ws + o_vst);
  unsigned* vct = (unsigned*)(ws + o_vct);
  ushort* y4 = (ushort*)(ws + o_y4);

  float* out_pool = (float*)d_out;
  float* out_unq  = out_pool + (size_t)n*16;

  {
    size_t n16 = zero_end/16;
    int zb = (int)((n16 + 255)/256); if (zb > 2048) zb = 2048;
    k_zero<<<zb,256,0,stream>>>((uint4*)ws, n16);
  }

  // weight prep (bf16, B-fragment order)
  k_wprep<<<8,256,0,stream>>>(w1, w1f, 9, 64);
  k_wprep<<<32,256,0,stream>>>(w2, w2f, 64, 128);
  k_wprep<<<128,256,0,stream>>>(w3, w3f, 128, 256);
  k_wprep<<<64,256,0,stream>>>(w4, w4f, 256, 64);

  int nb = (n + 255)/256;
  k_keys<<<nb,256,0,stream>>>(coords, cnt, n);
  k_scan1<<<NKEYS/1024,256,0,stream>>>(cnt, rloc, ploc, bsum);
  k_scan2<<<1,128,0,stream>>>(bsum, boff);
  k_unq<<<(NKEYS+255)/256,256,0,stream>>>(cnt, rloc, ploc, boff, out_unq, vst, vct);
  k_csr<<<nb,256,0,stream>>>(coords, ploc, boff, cursor, csr, n);

  // feats moments -> ac0 + analytic ac1
  k_stats0x<<<512,256,0,stream>>>(feats, sl0, n);
  k_fin01<<<1,64,0,stream>>>(sl0, 1.f/(float)n, g0, bb0, g1, bb1, w1, ac0, ac1);

  int gb = (n+63)/64;
  k_chain<2><<<gb,256,0,stream>>>(feats, ac0, w1f, ac1, w2f, ac2, w3f, ac3, w4f, b4, nullptr, nullptr, sl2, n);
  k_fin<<<2,64,0,stream>>>(sl2, 128, 1.f/(float)n, g2, bb2, ac2);

  k_chain<3><<<gb,256,0,stream>>>(feats, ac0, w1f, ac1, w2f, ac2, w3f, ac3, w4f, b4, nullptr, nullptr, sl3, n);
  k_fin<<<4,64,0,stream>>>(sl3, 256, 1.f/(float)n, g3, bb3, ac3);

  k_chain<4><<<gb,256,0,stream>>>(feats, ac0, w1f, ac1, w2f, ac2, w3f, ac3, w4f, b4, csr, y4, nullptr, n);

  // real voxels: M <= NKEYS, so this grid always covers them
  int maxv = (n < NKEYS) ? n : NKEYS;
  k_pool<<<(maxv + 4*VPW - 1)/(4*VPW),256,0,stream>>>(y4, vst, vct, boff, wp, bp, out_pool, n);
  k_fill<<<nb,256,0,stream>>>(boff, bp, out_pool, out_unq, n);
}

// Round 10
// 301.552 us; speedup vs baseline: 1.2698x; 1.0570x over previous
//
#include <hip/hip_runtime.h>
#include <hip/hip_bf16.h>

#define EPSBN 1e-5f
#define NKEYS 110592   // 48^3
#define SLICES 64
#define VPW 8          // voxels per wave in k_pool

typedef __attribute__((ext_vector_type(8))) short bf16x8;
typedef __attribute__((ext_vector_type(4))) float f32x4;

__device__ __forceinline__ float bf2f(ushort u){ return __uint_as_float(((unsigned)u)<<16); }
__device__ __forceinline__ ushort f2bf(float f){
  unsigned u = __float_as_uint(f);
  unsigned r = u + 0x7fffu + ((u>>16)&1u);
  return (ushort)(r>>16);
}

// XOR-swizzled byte offset in row-major [R][KP] bf16 tile (bank-conflict fix).
template<int KP>
__device__ __forceinline__ int swz(int row, int kbyte){
  constexpr int MASK = (KP >= 64) ? 7 : 3;
  return row*(KP*2) + (kbyte ^ ((row & MASK) << 4));
}

__device__ __forceinline__ int tri(int k, int l){
  if (k > l){ int t=k; k=l; l=t; }
  return k*9 - (k*(k-1))/2 + (l-k);
}

// ---------------- zero scratch ----------------
__global__ __launch_bounds__(256) void k_zero(uint4* __restrict__ p, size_t n16){
  size_t i = (size_t)blockIdx.x*256 + threadIdx.x;
  size_t stride = (size_t)gridDim.x*256;
  uint4 z = make_uint4(0,0,0,0);
  for (; i < n16; i += stride) p[i] = z;
}

// ---------------- weight prep: f32 [K][M] -> B-fragment order ----------------
__global__ __launch_bounds__(256) void k_wprep(const float* __restrict__ w,
    ushort* __restrict__ wf, int K, int M){
  int CT = M >> 4;
  int KS = (K + 31) >> 5;
  int total = KS*CT*512;
  for (int idx = blockIdx.x*256 + threadIdx.x; idx < total; idx += gridDim.x*256){
    int e = idx & 7, l = (idx>>3) & 63, c = idx >> 9;
    int ct = c % CT, ks = c / CT;
    int g = l >> 4, j = l & 15;
    int k = ks*32 + g*8 + e, col = ct*16 + j;
    wf[idx] = (k < K) ? f2bf(w[(size_t)k*M + col]) : (ushort)0;
  }
}

// ---------------- voxel unique ----------------
__global__ __launch_bounds__(256) void k_keys(const int* __restrict__ coords,
    unsigned* __restrict__ cnt, int n){
  int i = blockIdx.x*256 + threadIdx.x;
  if (i >= n) return;
  int x = coords[3*i+0], y = coords[3*i+1], z = coords[3*i+2];
  atomicAdd(&cnt[(unsigned)((x*48 + y)*48 + z)], 1u);
}

// pair-scan: flags (occupancy) AND counts, per 1024-key chunk
__global__ __launch_bounds__(256) void k_scan1(const unsigned* __restrict__ cnt,
    unsigned* __restrict__ rloc, unsigned* __restrict__ ploc, unsigned* __restrict__ bsum){
  __shared__ unsigned tf[256], tc[256];
  int t = threadIdx.x;
  int base = blockIdx.x*1024 + t*4;
  uint4 cv = *(const uint4*)&cnt[base];
  unsigned f0 = cv.x?1u:0u, f1 = cv.y?1u:0u, f2 = cv.z?1u:0u, f3 = cv.w?1u:0u;
  unsigned sf = f0+f1+f2+f3;
  unsigned sc = cv.x+cv.y+cv.z+cv.w;
  tf[t] = sf; tc[t] = sc;
  __syncthreads();
  for (int off=1; off<256; off<<=1){
    unsigned af = (t>=off) ? tf[t-off] : 0u;
    unsigned ac = (t>=off) ? tc[t-off] : 0u;
    __syncthreads();
    tf[t] += af; tc[t] += ac;
    __syncthreads();
  }
  unsigned rf = tf[t] - sf, rc = tc[t] - sc;
  rloc[base+0] = rf; rf += f0;    ploc[base+0] = rc; rc += cv.x;
  rloc[base+1] = rf; rf += f1;    ploc[base+1] = rc; rc += cv.y;
  rloc[base+2] = rf; rf += f2;    ploc[base+2] = rc; rc += cv.z;
  rloc[base+3] = rf;              ploc[base+3] = rc;
  if (t == 255){ bsum[2*blockIdx.x] = tf[255]; bsum[2*blockIdx.x+1] = tc[255]; }
}

__global__ __launch_bounds__(128) void k_scan2(const unsigned* __restrict__ bsum,
    unsigned* __restrict__ boff){
  __shared__ unsigned tf[128], tc[128];
  int t = threadIdx.x;
  unsigned vf = (t < 108) ? bsum[2*t] : 0u;
  unsigned vc = (t < 108) ? bsum[2*t+1] : 0u;
  tf[t] = vf; tc[t] = vc;
  __syncthreads();
  for (int off=1; off<128; off<<=1){
    unsigned af = (t>=off) ? tf[t-off] : 0u;
    unsigned ac = (t>=off) ? tc[t-off] : 0u;
    __syncthreads();
    tf[t] += af; tc[t] += ac;
    __syncthreads();
  }
  boff[2*t] = tf[t] - vf;     // flag-offset; boff[216] = total M
  boff[2*t+1] = tc[t] - vc;   // count-offset
}

// unique rows + per-voxel CSR geometry (start, count)
__global__ __launch_bounds__(256) void k_unq(const unsigned* __restrict__ cnt,
    const unsigned* __restrict__ rloc, const unsigned* __restrict__ ploc,
    const unsigned* __restrict__ boff, float* __restrict__ unq,
    unsigned* __restrict__ vst, unsigned* __restrict__ vct){
  int k = blockIdx.x*256 + threadIdx.x;
  if (k >= NKEYS) return;
  unsigned c = cnt[k];
  if (c == 0) return;
  unsigned r  = rloc[k] + boff[2*(k>>10)];
  unsigned st = ploc[k] + boff[2*(k>>10)+1];
  float z = (float)(k % 48);
  float y = (float)((k/48) % 48);
  float x = (float)(k / 2304);
  unq[3*(size_t)r+0] = x; unq[3*(size_t)r+1] = y; unq[3*(size_t)r+2] = z;
  vst[r] = st; vct[r] = c;
}

// place each point into its voxel's CSR slot
__global__ __launch_bounds__(256) void k_csr(const int* __restrict__ coords,
    const unsigned* __restrict__ ploc, const unsigned* __restrict__ boff,
    unsigned* __restrict__ cursor, unsigned* __restrict__ csr, int n){
  int i = blockIdx.x*256 + threadIdx.x;
  if (i >= n) return;
  int x = coords[3*i+0], y = coords[3*i+1], z = coords[3*i+2];
  unsigned k = (unsigned)((x*48 + y)*48 + z);
  unsigned slot = atomicAdd(&cursor[k], 1u);
  unsigned st = ploc[k] + boff[2*(k>>10)+1];
  csr[st + slot] = i;
}

// ---------------- feats moments: s[9] = sum x, q[45] = sum x_k x_l (k<=l) ----------------
__global__ __launch_bounds__(256) void k_stats0x(const float* __restrict__ X,
    float* __restrict__ slices, int n){
  float s[9], q[45];
  #pragma unroll
  for (int k=0;k<9;k++) s[k]=0.f;
  #pragma unroll
  for (int i=0;i<45;i++) q[i]=0.f;
  int stride = gridDim.x*256;
  for (int i = blockIdx.x*256 + threadIdx.x; i < n; i += stride){
    float v[9];
    #pragma unroll
    for (int k=0;k<9;k++) v[k] = X[(size_t)i*9+k];
    int qi=0;
    #pragma unroll
    for (int k=0;k<9;k++){
      s[k] += v[k];
      #pragma unroll
      for (int l=k;l<9;l++) q[qi++] += v[k]*v[l];
    }
  }
  #pragma unroll
  for (int off=32; off>0; off>>=1){
    #pragma unroll
    for (int k=0;k<9;k++)  s[k] += __shfl_down(s[k], off, 64);
    #pragma unroll
    for (int i=0;i<45;i++) q[i] += __shfl_down(q[i], off, 64);
  }
  if ((threadIdx.x & 63) == 0){
    float* sl = slices + (size_t)(blockIdx.x & (SLICES-1))*54;
    #pragma unroll
    for (int k=0;k<9;k++)  atomicAdd(&sl[k],   s[k]);
    #pragma unroll
    for (int i=0;i<45;i++) atomicAdd(&sl[9+i], q[i]);
  }
}

// ---------------- ac0 + analytic ac1 from feats moments (parallel, spill-free) ----------------
// u_k = a0_k x_k + c0_k ; t1_j = sum_k u_k w1[k][j] (bias-free raw convention)
__global__ __launch_bounds__(256) void k_fin01(const float* __restrict__ slices, float invN,
    const float* __restrict__ g0, const float* __restrict__ b0,
    const float* __restrict__ g1, const float* __restrict__ b1,
    const float* __restrict__ w1, float* __restrict__ ac0, float* __restrict__ ac1){
  __shared__ float pa[4][64];
  __shared__ float red[54];          // summed moments
  __shared__ float ms[9], a0s[9], c0s[9];
  int t = threadIdx.x;
  // phase A: parallel slice reduction (4 chunks x 54 cols)
  {
    int col = t & 63, ch = t >> 6;
    float a = 0.f;
    if (col < 54){
      #pragma unroll 4
      for (int sl = ch*16; sl < ch*16 + 16; sl++) a += slices[(size_t)sl*54 + col];
    }
    pa[ch][col] = a;
  }
  __syncthreads();
  if (t < 54) red[t] = pa[0][t] + pa[1][t] + pa[2][t] + pa[3][t];
  __syncthreads();
  // phase B: bn0 affine
  if (t < 9){
    float m = red[t]*invN;
    float var = red[9 + tri(t,t)]*invN - m*m;
    float a0 = g0[t]*rsqrtf(var + EPSBN);
    float c0 = b0[t] - m*a0;
    ms[t] = m; a0s[t] = a0; c0s[t] = c0;
    ac0[t] = a0; ac0[9+t] = c0;
  }
  __syncthreads();
  // phase C: analytic bn1 per output j (LDS broadcast reads, no spills)
  if (t < 64){
    float wj[9];
    #pragma unroll
    for (int k=0;k<9;k++) wj[k] = w1[(size_t)k*64 + t];
    float mean = 0.f;
    #pragma unroll
    for (int k=0;k<9;k++) mean += (ms[k]*a0s[k] + c0s[k])*wj[k];
    float e2 = 0.f;
    #pragma unroll
    for (int k=0;k<9;k++)
      #pragma unroll
      for (int l=0;l<9;l++){
        float U = a0s[k]*a0s[l]*(red[9 + tri(k,l)]*invN)
                + a0s[k]*c0s[l]*ms[k] + a0s[l]*c0s[k]*ms[l] + c0s[k]*c0s[l];
        e2 += wj[k]*wj[l]*U;
      }
    float var = e2 - mean*mean;
    float a = g1[t]*rsqrtf(var + EPSBN);
    ac1[t] = a;
    ac1[64+t] = b1[t] - mean*a;
  }
}

// reduce slices -> a = g*rsqrt(var+eps), c = b - mean*a.  Parallel version:
// 256 thr/block, 64 cols/block; thread (chunk=t>>6, col=t&63) sums 16 slices.
__global__ __launch_bounds__(256) void k_fin(const float* __restrict__ slices, int M, float invN,
    const float* __restrict__ g, const float* __restrict__ b, float* __restrict__ ac){
  __shared__ float ps[4][64], pss[4][64];
  int t = threadIdx.x;
  int col = t & 63, ch = t >> 6;
  int j = blockIdx.x*64 + col;
  float s = 0.f, ss = 0.f;
  #pragma unroll 4
  for (int sl = ch*16; sl < ch*16 + 16; sl++){
    s  += slices[(size_t)sl*2*M + j];
    ss += slices[(size_t)sl*2*M + M + j];
  }
  ps[ch][col] = s; pss[ch][col] = ss;
  __syncthreads();
  if (t < 64){
    j = blockIdx.x*64 + t;
    float S  = ps[0][t]+ps[1][t]+ps[2][t]+ps[3][t];
    float SS = pss[0][t]+pss[1][t]+pss[2][t]+pss[3][t];
    float mean = S*invN;
    float var = SS*invN - mean*mean;
    float a = g[j]*rsqrtf(var + EPSBN);
    ac[j] = a;
    ac[M+j] = b[j] - mean*a;
  }
}

// ---------------- fused MFMA recompute chain, barrier-free weight streaming ----------------
// 64 rows/block, 4 waves. DEPTH=2: t2 stats. DEPTH=3: t3 stats.
// DEPTH=4: rows gathered via csr; dense y4 store in CSR order.
template<int DEPTH>
__global__ __launch_bounds__(256,2) void k_chain(
    const float* __restrict__ feats, const float* __restrict__ ac0,
    const ushort* __restrict__ w1f, const float* __restrict__ ac1,
    const ushort* __restrict__ w2f, const float* __restrict__ ac2,
    const ushort* __restrict__ w3f, const float* __restrict__ ac3,
    const ushort* __restrict__ w4f, const float* __restrict__ b4,
    const unsigned* __restrict__ csr, ushort* __restrict__ y4,
    float* __restrict__ slices, int n){
  constexpr int SMEM = (DEPTH==2) ? 12288 : (DEPTH==3) ? 28672 : 32768;
  __shared__ __align__(16) char smem[SMEM];
  __shared__ unsigned rid_s[64];
  char* X0 = smem;                  // [64][32]  bf16 swz<32>,  4KB

  int t = threadIdx.x;
  int lane = t & 63, w = t >> 6;
  int lrow = lane & 15, lgrp = lane >> 4;
  int rowbase = blockIdx.x * 64;

  // stage-1 B-frag (issued before staging; overlaps)
  bf16x8 b1 = *(const bf16x8*)(w1f + (size_t)(w*64 + lane)*8);

  if constexpr (DEPTH == 4){
    if (t < 64){
      int gr = rowbase + t;
      rid_s[t] = (gr < n) ? csr[gr] : 0u;
    }
    __syncthreads();
  }

  // ---- X0 = bn0(feats), K padded to 32, rows >= n zeroed ----
  for (int e = t; e < 2048; e += 256){
    int row = e >> 5, k = e & 31;
    int gr = rowbase + row;
    size_t rid = (DEPTH == 4) ? (size_t)rid_s[row] : (size_t)gr;
    float v = (k < 9 && gr < n) ? fmaf(feats[rid*9 + k], ac0[k], ac0[9+k]) : 0.f;
    *(ushort*)(X0 + swz<32>(row, k*2)) = f2bf(v);
  }
  __syncthreads();

  // ---- stage 1: t1 = X0 @ w1 (wave w: cols 16w..16w+16) ----
  f32x4 acc0[4] = {};
  #pragma unroll
  for (int rb = 0; rb < 4; rb++){
    bf16x8 a = *(const bf16x8*)(X0 + swz<32>(rb*16 + lrow, lgrp*16));
    acc0[rb] = __builtin_amdgcn_mfma_f32_16x16x32_bf16(a, b1, acc0[rb], 0,0,0);
  }

  char* T1 = smem + 4096;           // [64][64] bf16 swz<64>, 8KB
  // ---- T1 = bf16(relu(bn1(t1))), rows >= n zeroed ----
  {
    int j = w*16 + lrow;
    float a1 = ac1[j], c1 = ac1[64+j];
    #pragma unroll
    for (int rb=0;rb<4;rb++)
      #pragma unroll
      for (int r=0;r<4;r++){
        int row = rb*16 + 4*lgrp + r;
        float v = fmaxf(fmaf(acc0[rb][r], a1, c1), 0.f);
        if (rowbase + row >= n) v = 0.f;
        *(ushort*)(T1 + swz<64>(row, j*2)) = f2bf(v);
      }
  }
  __syncthreads();

  // ---- stage 2: 64x64 @ 64x128 (wave w: cols 32w..32w+32) ----
  f32x4 acc1[4][2] = {};
  #pragma unroll
  for (int ks=0; ks<2; ks++){
    bf16x8 bb[2];
    #pragma unroll
    for (int f=0;f<2;f++)
      bb[f] = *(const bf16x8*)(w2f + (size_t)((ks*8 + 2*w + f)*64 + lane)*8);
    #pragma unroll
    for (int rb=0;rb<4;rb++){
      bf16x8 a = *(const bf16x8*)(T1 + swz<64>(rb*16 + lrow, ks*64 + lgrp*16));
      #pragma unroll
      for (int f=0;f<2;f++)
        acc1[rb][f] = __builtin_amdgcn_mfma_f32_16x16x32_bf16(a, bb[f], acc1[rb][f], 0,0,0);
    }
  }

  if constexpr (DEPTH == 2){
    float s[2]={0.f,0.f}, ss[2]={0.f,0.f};
    #pragma unroll
    for (int rb=0;rb<4;rb++)
      #pragma unroll
      for (int f=0;f<2;f++)
        #pragma unroll
        for (int r=0;r<4;r++){ float v=acc1[rb][f][r]; s[f]+=v; ss[f]+=v*v; }
    __syncthreads();
    float* ssum = (float*)smem;
    ssum[t] = 0.f;
    __syncthreads();
    #pragma unroll
    for (int f=0;f<2;f++){
      int j = w*32 + 16*f + lrow;
      atomicAdd(&ssum[j], s[f]); atomicAdd(&ssum[128+j], ss[f]);
    }
    __syncthreads();
    float* gsl = slices + (size_t)(blockIdx.x & (SLICES-1))*256;
    atomicAdd(&gsl[t], ssum[t]);
    return;
  }

  if constexpr (DEPTH >= 3){
  char* T2 = smem + 12288;          // [64][128] bf16 swz<128>, 16KB
  // ---- T2 = bf16(relu(bn2(t2))), rows >= n zeroed ----
  #pragma unroll
  for (int f=0;f<2;f++){
    int j = w*32 + 16*f + lrow;
    float a2 = ac2[j], c2 = ac2[128+j];
    #pragma unroll
    for (int rb=0;rb<4;rb++)
      #pragma unroll
      for (int r=0;r<4;r++){
        int row = rb*16 + 4*lgrp + r;
        float v = fmaxf(fmaf(acc1[rb][f][r], a2, c2), 0.f);
        if (rowbase + row >= n) v = 0.f;
        *(ushort*)(T2 + swz<128>(row, j*2)) = f2bf(v);
      }
  }
  __syncthreads();

  if constexpr (DEPTH == 3){
    // ---- stage 3 (stats only): two 32-col halves to cap VGPR ----
    float s3[2][2], ss3[2][2];
    #pragma unroll
    for (int h=0; h<2; h++){
      f32x4 acc2[4][2] = {};
      #pragma unroll
      for (int ks=0; ks<4; ks++){
        bf16x8 bb[2];
        #pragma unroll
        for (int f=0;f<2;f++)
          bb[f] = *(const bf16x8*)(w3f + (size_t)((ks*16 + 4*w + 2*h + f)*64 + lane)*8);
        #pragma unroll
        for (int rb=0;rb<4;rb++){
          bf16x8 a = *(const bf16x8*)(T2 + swz<128>(rb*16 + lrow, ks*64 + lgrp*16));
          #pragma unroll
          for (int f=0;f<2;f++)
            acc2[rb][f] = __builtin_amdgcn_mfma_f32_16x16x32_bf16(a, bb[f], acc2[rb][f], 0,0,0);
        }
      }
      #pragma unroll
      for (int f=0;f<2;f++){
        float s=0.f, ss=0.f;
        #pragma unroll
        for (int rb=0;rb<4;rb++)
          #pragma unroll
          for (int r=0;r<4;r++){ float v=acc2[rb][f][r]; s+=v; ss+=v*v; }
        s3[h][f]=s; ss3[h][f]=ss;
      }
    }
    __syncthreads();
    float* ssum = (float*)smem;
    for (int e=t; e<512; e+=256) ssum[e] = 0.f;
    __syncthreads();
    #pragma unroll
    for (int h=0;h<2;h++)
      #pragma unroll
      for (int f=0;f<2;f++){
        int j = 64*w + 32*h + 16*f + lrow;
        atomicAdd(&ssum[j], s3[h][f]); atomicAdd(&ssum[256+j], ss3[h][f]);
      }
    __syncthreads();
    float* gsl = slices + (size_t)(blockIdx.x & (SLICES-1))*512;
    for (int e=t; e<512; e+=256) atomicAdd(&gsl[e], ssum[e]);
    return;
  }

  if constexpr (DEPTH == 4){
  // ---- stage 3 full into registers: wave w owns cols 64w..64w+64 ----
  f32x4 acc2[4][4] = {};
  #pragma unroll
  for (int ks=0; ks<4; ks++){
    bf16x8 bb[4];
    #pragma unroll
    for (int f=0;f<4;f++)
      bb[f] = *(const bf16x8*)(w3f + (size_t)((ks*16 + 4*w + f)*64 + lane)*8);
    #pragma unroll
    for (int rb=0;rb<4;rb++){
      bf16x8 a = *(const bf16x8*)(T2 + swz<128>(rb*16 + lrow, ks*64 + lgrp*16));
      #pragma unroll
      for (int f=0;f<4;f++)
        acc2[rb][f] = __builtin_amdgcn_mfma_f32_16x16x32_bf16(a, bb[f], acc2[rb][f], 0,0,0);
    }
  }
  __syncthreads();   // T2 (and X0/T1) dead -> X3 aliases smem base

  // ---- X3 = bf16(relu(bn3(t3))) at smem+0, [64][256] swz<256>, 32KB ----
  char* X3 = smem;
  #pragma unroll
  for (int f=0;f<4;f++){
    int j = 64*w + 16*f + lrow;
    float a3 = ac3[j], c3 = ac3[256+j];
    #pragma unroll
    for (int rb=0;rb<4;rb++)
      #pragma unroll
      for (int r=0;r<4;r++){
        int row = rb*16 + 4*lgrp + r;
        float v = fmaxf(fmaf(acc2[rb][f][r], a3, c3), 0.f);
        if (rowbase + row >= n) v = 0.f;
        *(ushort*)(X3 + swz<256>(row, j*2)) = f2bf(v);
      }
  }
  __syncthreads();

  // ---- stage 4: 64x256 @ 256x64 (wave w: cols 16w..16w+16) ----
  f32x4 acc3[4] = {};
  #pragma unroll
  for (int ks=0; ks<8; ks++){
    bf16x8 b = *(const bf16x8*)(w4f + (size_t)((ks*4 + w)*64 + lane)*8);
    #pragma unroll
    for (int rb=0;rb<4;rb++){
      bf16x8 a = *(const bf16x8*)(X3 + swz<256>(rb*16 + lrow, ks*64 + lgrp*16));
      acc3[rb] = __builtin_amdgcn_mfma_f32_16x16x32_bf16(a, b, acc3[rb], 0,0,0);
    }
  }

  // ---- dense store (CSR order): y4[gr][j] = t4 + b4 ----
  {
    int j = w*16 + lrow;
    float bias4 = b4[j];
    #pragma unroll
    for (int rb=0;rb<4;rb++)
      #pragma unroll
      for (int r=0;r<4;r++){
        int gr = rowbase + 16*rb + 4*lgrp + r;
        if (gr < n) y4[(size_t)gr*64 + j] = f2bf(acc3[rb][r] + bias4);
      }
  }
  } // DEPTH==4
  } // DEPTH>=3
}

// ---------------- pool: lane = channel, contiguous CSR rows, 8 voxels/wave ----------------
__global__ __launch_bounds__(256) void k_pool(const ushort* __restrict__ y4,
    const unsigned* __restrict__ vst, const unsigned* __restrict__ vct,
    const unsigned* __restrict__ boff, const float* __restrict__ wp,
    const float* __restrict__ bp, float* __restrict__ out, int n){
  __shared__ float wpsT[1024];      // [16][64]: wpsT[j*64+ch] = wp[ch][j]
  __shared__ float sm[4][64];
  int t = threadIdx.x, w = t >> 6, lane = t & 63;
  for (int e=t; e<1024; e+=256){
    int j = e >> 6, ch = e & 63;
    wpsT[e] = wp[ch*16 + j];
  }
  __syncthreads();
  unsigned M = boff[216];
  int base = blockIdx.x*(4*VPW) + w*VPW;
  if (base >= (int)M) return;
  float bpv = (lane < 16) ? bp[lane] : 0.f;
  int q = lane >> 4, j = lane & 15;
  int vend = (int)M - base; if (vend > VPW) vend = VPW;
  for (int v = 0; v < vend; v++){
    int r = base + v;
    unsigned st = vst[r], c = vct[r];
    const ushort* row = y4 + (size_t)st*64 + lane;
    float m = bf2f(row[0]);
    #pragma unroll 4
    for (unsigned pp = 1; pp < c; pp++)
      m = fmaxf(m, bf2f(row[(size_t)pp*64]));
    sm[w][lane] = m;                // wave-private: no barrier needed
    float acc = 0.f;
    #pragma unroll
    for (int i=0;i<16;i++) acc = fmaf(sm[w][q*16+i], wpsT[j*64 + q*16+i], acc);
    acc += __shfl_xor(acc, 16, 64);
    acc += __shfl_xor(acc, 32, 64);
    if (lane < 16) out[(size_t)r*16 + lane] = fmaxf(acc + bpv, 0.f);
  }
}

// ---------------- padding rows: out = relu(bp), unq = -1 ----------------
__global__ __launch_bounds__(256) void k_fill(const unsigned* __restrict__ boff,
    const float* __restrict__ bp, float* __restrict__ out,
    float* __restrict__ unq, int n){
  int r = blockIdx.x*256 + threadIdx.x;
  if (r >= n) return;
  unsigned M = boff[216];
  if ((unsigned)r < M) return;
  #pragma unroll
  for (int j=0;j<16;j++) out[(size_t)r*16 + j] = fmaxf(bp[j], 0.f);
  unq[3*(size_t)r+0] = -1.f; unq[3*(size_t)r+1] = -1.f; unq[3*(size_t)r+2] = -1.f;
}

extern "C" void kernel_launch(void* const* d_in, const int* in_sizes, int n_in,
                              void* d_out, int out_size, void* d_ws, size_t ws_size,
                              hipStream_t stream){
  (void)n_in; (void)out_size;
  const float* feats  = (const float*)d_in[0];
  const int*   coords = (const int*)d_in[1];
  const float* g0=(const float*)d_in[2];  const float* bb0=(const float*)d_in[3];
  const float* g1=(const float*)d_in[4];  const float* bb1=(const float*)d_in[5];
  const float* g2=(const float*)d_in[6];  const float* bb2=(const float*)d_in[7];
  const float* g3=(const float*)d_in[8];  const float* bb3=(const float*)d_in[9];
  const float* w1=(const float*)d_in[10];
  const float* w2=(const float*)d_in[12];
  const float* w3=(const float*)d_in[14];
  const float* w4=(const float*)d_in[16]; const float* b4=(const float*)d_in[17];
  const float* wp=(const float*)d_in[18]; const float* bp=(const float*)d_in[19];
  int n = in_sizes[0]/9;

  char* ws = (char*)d_ws;
  size_t off = 0;
  auto alloc = [&](size_t bytes){ size_t o = off; off = (off + bytes + 255) & ~(size_t)255; return o; };
  size_t o_cnt  = alloc((size_t)NKEYS*4);            // zeroed
  size_t o_cur  = alloc((size_t)NKEYS*4);            // zeroed (csr cursors)
  size_t o_sl0  = alloc((size_t)SLICES*54*4);        // zeroed
  size_t o_sl2  = alloc((size_t)SLICES*256*4);       // zeroed
  size_t o_sl3  = alloc((size_t)SLICES*512*4);       // zeroed
  size_t zero_end = off;
  size_t o_rloc = alloc((size_t)NKEYS*4);
  size_t o_ploc = alloc((size_t)NKEYS*4);
  size_t o_bsum = alloc(256*4);
  size_t o_boff = alloc(256*4);
  size_t o_ac0  = alloc(18*4);
  size_t o_ac1  = alloc(128*4);
  size_t o_ac2  = alloc(256*4);
  size_t o_ac3  = alloc(512*4);
  size_t o_w1f  = alloc(2048*2);
  size_t o_w2f  = alloc(8192*2);
  size_t o_w3f  = alloc(32768*2);
  size_t o_w4f  = alloc(16384*2);
  size_t o_csr  = alloc((size_t)n*4);
  size_t o_vst  = alloc((size_t)n*4);
  size_t o_vct  = alloc((size_t)n*4);
  size_t o_y4   = alloc((size_t)n*64*2);
  if (ws_size < off) return;                         // clean fail if ws too small

  unsigned* cnt  = (unsigned*)(ws + o_cnt);
  unsigned* cursor = (unsigned*)(ws + o_cur);
  unsigned* rloc = (unsigned*)(ws + o_rloc);
  unsigned* ploc = (unsigned*)(ws + o_ploc);
  unsigned* bsum = (unsigned*)(ws + o_bsum);
  unsigned* boff = (unsigned*)(ws + o_boff);
  float* sl0 = (float*)(ws + o_sl0);
  float* sl2 = (float*)(ws + o_sl2);
  float* sl3 = (float*)(ws + o_sl3);
  float* ac0 = (float*)(ws + o_ac0);
  float* ac1 = (float*)(ws + o_ac1);
  float* ac2 = (float*)(ws + o_ac2);
  float* ac3 = (float*)(ws + o_ac3);
  ushort* w1f = (ushort*)(ws + o_w1f);
  ushort* w2f = (ushort*)(ws + o_w2f);
  ushort* w3f = (ushort*)(ws + o_w3f);
  ushort* w4f = (ushort*)(ws + o_w4f);
  unsigned* csr = (unsigned*)(ws + o_csr);
  unsigned* vst = (unsigned*)(ws + o_vst);
  unsigned* vct = (unsigned*)(ws + o_vct);
  ushort* y4 = (ushort*)(ws + o_y4);

  float* out_pool = (float*)d_out;
  float* out_unq  = out_pool + (size_t)n*16;

  {
    size_t n16 = zero_end/16;
    int zb = (int)((n16 + 255)/256); if (zb > 2048) zb = 2048;
    k_zero<<<zb,256,0,stream>>>((uint4*)ws, n16);
  }

  // weight prep (bf16, B-fragment order)
  k_wprep<<<8,256,0,stream>>>(w1, w1f, 9, 64);
  k_wprep<<<32,256,0,stream>>>(w2, w2f, 64, 128);
  k_wprep<<<128,256,0,stream>>>(w3, w3f, 128, 256);
  k_wprep<<<64,256,0,stream>>>(w4, w4f, 256, 64);

  int nb = (n + 255)/256;
  k_keys<<<nb,256,0,stream>>>(coords, cnt, n);
  k_scan1<<<NKEYS/1024,256,0,stream>>>(cnt, rloc, ploc, bsum);
  k_scan2<<<1,128,0,stream>>>(bsum, boff);
  k_unq<<<(NKEYS+255)/256,256,0,stream>>>(cnt, rloc, ploc, boff, out_unq, vst, vct);
  k_csr<<<nb,256,0,stream>>>(coords, ploc, boff, cursor, csr, n);

  // feats moments -> ac0 + analytic ac1
  k_stats0x<<<512,256,0,stream>>>(feats, sl0, n);
  k_fin01<<<1,256,0,stream>>>(sl0, 1.f/(float)n, g0, bb0, g1, bb1, w1, ac0, ac1);

  int gb = (n+63)/64;
  k_chain<2><<<gb,256,0,stream>>>(feats, ac0, w1f, ac1, w2f, ac2, w3f, ac3, w4f, b4, nullptr, nullptr, sl2, n);
  k_fin<<<2,256,0,stream>>>(sl2, 128, 1.f/(float)n, g2, bb2, ac2);

  k_chain<3><<<gb,256,0,stream>>>(feats, ac0, w1f, ac1, w2f, ac2, w3f, ac3, w4f, b4, nullptr, nullptr, sl3, n);
  k_fin<<<4,256,0,stream>>>(sl3, 256, 1.f/(float)n, g3, bb3, ac3);

  k_chain<4><<<gb,256,0,stream>>>(feats, ac0, w1f, ac1, w2f, ac2, w3f, ac3, w4f, b4, csr, y4, nullptr, n);

  // real voxels: M <= NKEYS, so this grid always covers them
  int maxv = (n < NKEYS) ? n : NKEYS;
  k_pool<<<(maxv + 4*VPW - 1)/(4*VPW),256,0,stream>>>(y4, vst, vct, boff, wp, bp, out_pool, n);
  k_fill<<<nb,256,0,stream>>>(boff, bp, out_pool, out_unq, n);
}

// Round 12
// 288.677 us; speedup vs baseline: 1.3265x; 1.0446x over previous
//
#include <hip/hip_runtime.h>
#include <hip/hip_bf16.h>

#define EPSBN 1e-5f
#define NKEYS 110592   // 48^3
#define SLICES 64
#define VPW 8          // voxels per wave in k_pool

typedef __attribute__((ext_vector_type(8))) short bf16x8;
typedef __attribute__((ext_vector_type(4))) float f32x4;

__device__ __forceinline__ float bf2f(ushort u){ return __uint_as_float(((unsigned)u)<<16); }
__device__ __forceinline__ ushort f2bf(float f){
  unsigned u = __float_as_uint(f);
  unsigned r = u + 0x7fffu + ((u>>16)&1u);
  return (ushort)(r>>16);
}

// XOR-swizzled byte offset in row-major [R][KP] bf16 tile (bank-conflict fix).
template<int KP>
__device__ __forceinline__ int swz(int row, int kbyte){
  constexpr int MASK = (KP >= 64) ? 7 : 3;
  return row*(KP*2) + (kbyte ^ ((row & MASK) << 4));
}

__device__ __forceinline__ int tri(int k, int l){
  if (k > l){ int t=k; k=l; l=t; }
  return k*9 - (k*(k-1))/2 + (l-k);
}

// ---------------- zero scratch ----------------
__global__ __launch_bounds__(256) void k_zero(uint4* __restrict__ p, size_t n16){
  size_t i = (size_t)blockIdx.x*256 + threadIdx.x;
  size_t stride = (size_t)gridDim.x*256;
  uint4 z = make_uint4(0,0,0,0);
  for (; i < n16; i += stride) p[i] = z;
}

// ---------------- weight prep: f32 [K][M] -> B-fragment order ----------------
__global__ __launch_bounds__(256) void k_wprep(const float* __restrict__ w,
    ushort* __restrict__ wf, int K, int M){
  int CT = M >> 4;
  int KS = (K + 31) >> 5;
  int total = KS*CT*512;
  for (int idx = blockIdx.x*256 + threadIdx.x; idx < total; idx += gridDim.x*256){
    int e = idx & 7, l = (idx>>3) & 63, c = idx >> 9;
    int ct = c % CT, ks = c / CT;
    int g = l >> 4, j = l & 15;
    int k = ks*32 + g*8 + e, col = ct*16 + j;
    wf[idx] = (k < K) ? f2bf(w[(size_t)k*M + col]) : (ushort)0;
  }
}

// ---------------- voxel unique ----------------
__global__ __launch_bounds__(256) void k_keys(const int* __restrict__ coords,
    unsigned* __restrict__ cnt, int n){
  int i = blockIdx.x*256 + threadIdx.x;
  if (i >= n) return;
  int x = coords[3*i+0], y = coords[3*i+1], z = coords[3*i+2];
  atomicAdd(&cnt[(unsigned)((x*48 + y)*48 + z)], 1u);
}

// pair-scan: flags (occupancy) AND counts, per 1024-key chunk
__global__ __launch_bounds__(256) void k_scan1(const unsigned* __restrict__ cnt,
    unsigned* __restrict__ rloc, unsigned* __restrict__ ploc, unsigned* __restrict__ bsum){
  __shared__ unsigned tf[256], tc[256];
  int t = threadIdx.x;
  int base = blockIdx.x*1024 + t*4;
  uint4 cv = *(const uint4*)&cnt[base];
  unsigned f0 = cv.x?1u:0u, f1 = cv.y?1u:0u, f2 = cv.z?1u:0u, f3 = cv.w?1u:0u;
  unsigned sf = f0+f1+f2+f3;
  unsigned sc = cv.x+cv.y+cv.z+cv.w;
  tf[t] = sf; tc[t] = sc;
  __syncthreads();
  for (int off=1; off<256; off<<=1){
    unsigned af = (t>=off) ? tf[t-off] : 0u;
    unsigned ac = (t>=off) ? tc[t-off] : 0u;
    __syncthreads();
    tf[t] += af; tc[t] += ac;
    __syncthreads();
  }
  unsigned rf = tf[t] - sf, rc = tc[t] - sc;
  rloc[base+0] = rf; rf += f0;    ploc[base+0] = rc; rc += cv.x;
  rloc[base+1] = rf; rf += f1;    ploc[base+1] = rc; rc += cv.y;
  rloc[base+2] = rf; rf += f2;    ploc[base+2] = rc; rc += cv.z;
  rloc[base+3] = rf;              ploc[base+3] = rc;
  if (t == 255){ bsum[2*blockIdx.x] = tf[255]; bsum[2*blockIdx.x+1] = tc[255]; }
}

__global__ __launch_bounds__(128) void k_scan2(const unsigned* __restrict__ bsum,
    unsigned* __restrict__ boff){
  __shared__ unsigned tf[128], tc[128];
  int t = threadIdx.x;
  unsigned vf = (t < 108) ? bsum[2*t] : 0u;
  unsigned vc = (t < 108) ? bsum[2*t+1] : 0u;
  tf[t] = vf; tc[t] = vc;
  __syncthreads();
  for (int off=1; off<128; off<<=1){
    unsigned af = (t>=off) ? tf[t-off] : 0u;
    unsigned ac = (t>=off) ? tc[t-off] : 0u;
    __syncthreads();
    tf[t] += af; tc[t] += ac;
    __syncthreads();
  }
  boff[2*t] = tf[t] - vf;     // flag-offset; boff[216] = total M
  boff[2*t+1] = tc[t] - vc;   // count-offset
}

// unique rows + per-voxel CSR geometry (start, count)
__global__ __launch_bounds__(256) void k_unq(const unsigned* __restrict__ cnt,
    const unsigned* __restrict__ rloc, const unsigned* __restrict__ ploc,
    const unsigned* __restrict__ boff, float* __restrict__ unq,
    unsigned* __restrict__ vst, unsigned* __restrict__ vct){
  int k = blockIdx.x*256 + threadIdx.x;
  if (k >= NKEYS) return;
  unsigned c = cnt[k];
  if (c == 0) return;
  unsigned r  = rloc[k] + boff[2*(k>>10)];
  unsigned st = ploc[k] + boff[2*(k>>10)+1];
  float z = (float)(k % 48);
  float y = (float)((k/48) % 48);
  float x = (float)(k / 2304);
  unq[3*(size_t)r+0] = x; unq[3*(size_t)r+1] = y; unq[3*(size_t)r+2] = z;
  vst[r] = st; vct[r] = c;
}

// place each point into its voxel's CSR slot
__global__ __launch_bounds__(256) void k_csr(const int* __restrict__ coords,
    const unsigned* __restrict__ ploc, const unsigned* __restrict__ boff,
    unsigned* __restrict__ cursor, unsigned* __restrict__ csr, int n){
  int i = blockIdx.x*256 + threadIdx.x;
  if (i >= n) return;
  int x = coords[3*i+0], y = coords[3*i+1], z = coords[3*i+2];
  unsigned k = (unsigned)((x*48 + y)*48 + z);
  unsigned slot = atomicAdd(&cursor[k], 1u);
  unsigned st = ploc[k] + boff[2*(k>>10)+1];
  csr[st + slot] = i;
}

// ---------------- feats moments: s[9] = sum x, q[45] = sum x_k x_l (k<=l) ----------------
__global__ __launch_bounds__(256) void k_stats0x(const float* __restrict__ X,
    float* __restrict__ slices, int n){
  float s[9], q[45];
  #pragma unroll
  for (int k=0;k<9;k++) s[k]=0.f;
  #pragma unroll
  for (int i=0;i<45;i++) q[i]=0.f;
  int stride = gridDim.x*256;
  for (int i = blockIdx.x*256 + threadIdx.x; i < n; i += stride){
    float v[9];
    #pragma unroll
    for (int k=0;k<9;k++) v[k] = X[(size_t)i*9+k];
    int qi=0;
    #pragma unroll
    for (int k=0;k<9;k++){
      s[k] += v[k];
      #pragma unroll
      for (int l=k;l<9;l++) q[qi++] += v[k]*v[l];
    }
  }
  #pragma unroll
  for (int off=32; off>0; off>>=1){
    #pragma unroll
    for (int k=0;k<9;k++)  s[k] += __shfl_down(s[k], off, 64);
    #pragma unroll
    for (int i=0;i<45;i++) q[i] += __shfl_down(q[i], off, 64);
  }
  if ((threadIdx.x & 63) == 0){
    float* sl = slices + (size_t)(blockIdx.x & (SLICES-1))*54;
    #pragma unroll
    for (int k=0;k<9;k++)  atomicAdd(&sl[k],   s[k]);
    #pragma unroll
    for (int i=0;i<45;i++) atomicAdd(&sl[9+i], q[i]);
  }
}

// ---------------- ac0 + analytic ac1 from feats moments (parallel, spill-free) ----------------
__global__ __launch_bounds__(256) void k_fin01(const float* __restrict__ slices, float invN,
    const float* __restrict__ g0, const float* __restrict__ b0,
    const float* __restrict__ g1, const float* __restrict__ b1,
    const float* __restrict__ w1, float* __restrict__ ac0, float* __restrict__ ac1){
  __shared__ float pa[4][64];
  __shared__ float red[54];
  __shared__ float ms[9], a0s[9], c0s[9];
  int t = threadIdx.x;
  {
    int col = t & 63, ch = t >> 6;
    float a = 0.f;
    if (col < 54){
      #pragma unroll 4
      for (int sl = ch*16; sl < ch*16 + 16; sl++) a += slices[(size_t)sl*54 + col];
    }
    pa[ch][col] = a;
  }
  __syncthreads();
  if (t < 54) red[t] = pa[0][t] + pa[1][t] + pa[2][t] + pa[3][t];
  __syncthreads();
  if (t < 9){
    float m = red[t]*invN;
    float var = red[9 + tri(t,t)]*invN - m*m;
    float a0 = g0[t]*rsqrtf(var + EPSBN);
    float c0 = b0[t] - m*a0;
    ms[t] = m; a0s[t] = a0; c0s[t] = c0;
    ac0[t] = a0; ac0[9+t] = c0;
  }
  __syncthreads();
  if (t < 64){
    float wj[9];
    #pragma unroll
    for (int k=0;k<9;k++) wj[k] = w1[(size_t)k*64 + t];
    float mean = 0.f;
    #pragma unroll
    for (int k=0;k<9;k++) mean += (ms[k]*a0s[k] + c0s[k])*wj[k];
    float e2 = 0.f;
    #pragma unroll
    for (int k=0;k<9;k++)
      #pragma unroll
      for (int l=0;l<9;l++){
        float U = a0s[k]*a0s[l]*(red[9 + tri(k,l)]*invN)
                + a0s[k]*c0s[l]*ms[k] + a0s[l]*c0s[k]*ms[l] + c0s[k]*c0s[l];
        e2 += wj[k]*wj[l]*U;
      }
    float var = e2 - mean*mean;
    float a = g1[t]*rsqrtf(var + EPSBN);
    ac1[t] = a;
    ac1[64+t] = b1[t] - mean*a;
  }
}

// parallel slice finalize
__global__ __launch_bounds__(256) void k_fin(const float* __restrict__ slices, int M, float invN,
    const float* __restrict__ g, const float* __restrict__ b, float* __restrict__ ac){
  __shared__ float ps[4][64], pss[4][64];
  int t = threadIdx.x;
  int col = t & 63, ch = t >> 6;
  int j = blockIdx.x*64 + col;
  float s = 0.f, ss = 0.f;
  #pragma unroll 4
  for (int sl = ch*16; sl < ch*16 + 16; sl++){
    s  += slices[(size_t)sl*2*M + j];
    ss += slices[(size_t)sl*2*M + M + j];
  }
  ps[ch][col] = s; pss[ch][col] = ss;
  __syncthreads();
  if (t < 64){
    j = blockIdx.x*64 + t;
    float S  = ps[0][t]+ps[1][t]+ps[2][t]+ps[3][t];
    float SS = pss[0][t]+pss[1][t]+pss[2][t]+pss[3][t];
    float mean = S*invN;
    float var = SS*invN - mean*mean;
    float a = g[j]*rsqrtf(var + EPSBN);
    ac[j] = a;
    ac[M+j] = b[j] - mean*a;
  }
}

// ================= BIG-WS FAST PATH =================
// pass 1: feats (csr-gathered) -> stage1 -> bn1 -> stage2; store raw t2 bf16 (CSR order); t2 stats
__global__ __launch_bounds__(256,2) void k_chain12(
    const float* __restrict__ feats, const float* __restrict__ ac0,
    const ushort* __restrict__ w1f, const float* __restrict__ ac1,
    const ushort* __restrict__ w2f, const unsigned* __restrict__ csr,
    ushort* __restrict__ t2, float* __restrict__ slices, int n){
  __shared__ __align__(16) char smem[12288];
  __shared__ unsigned rid_s[64];
  char* X0 = smem;                  // [64][32] bf16 swz<32>, 4KB
  char* T1 = smem + 4096;           // [64][64] bf16 swz<64>, 8KB
  int t = threadIdx.x;
  int lane = t & 63, w = t >> 6;
  int lrow = lane & 15, lgrp = lane >> 4;
  int rowbase = blockIdx.x * 64;

  bf16x8 b1 = *(const bf16x8*)(w1f + (size_t)(w*64 + lane)*8);
  if (t < 64){
    int gr = rowbase + t;
    rid_s[t] = (gr < n) ? csr[gr] : 0u;
  }
  __syncthreads();
  for (int e = t; e < 2048; e += 256){
    int row = e >> 5, k = e & 31;
    int gr = rowbase + row;
    float v = (k < 9 && gr < n) ? fmaf(feats[(size_t)rid_s[row]*9 + k], ac0[k], ac0[9+k]) : 0.f;
    *(ushort*)(X0 + swz<32>(row, k*2)) = f2bf(v);
  }
  __syncthreads();

  f32x4 acc0[4] = {};
  #pragma unroll
  for (int rb = 0; rb < 4; rb++){
    bf16x8 a = *(const bf16x8*)(X0 + swz<32>(rb*16 + lrow, lgrp*16));
    acc0[rb] = __builtin_amdgcn_mfma_f32_16x16x32_bf16(a, b1, acc0[rb], 0,0,0);
  }
  {
    int j = w*16 + lrow;
    float a1 = ac1[j], c1 = ac1[64+j];
    #pragma unroll
    for (int rb=0;rb<4;rb++)
      #pragma unroll
      for (int r=0;r<4;r++){
        int row = rb*16 + 4*lgrp + r;
        float v = fmaxf(fmaf(acc0[rb][r], a1, c1), 0.f);
        if (rowbase + row >= n) v = 0.f;
        *(ushort*)(T1 + swz<64>(row, j*2)) = f2bf(v);
      }
  }
  __syncthreads();

  f32x4 acc1[4][2] = {};
  #pragma unroll
  for (int ks=0; ks<2; ks++){
    bf16x8 bb[2];
    #pragma unroll
    for (int f=0;f<2;f++)
      bb[f] = *(const bf16x8*)(w2f + (size_t)((ks*8 + 2*w + f)*64 + lane)*8);
    #pragma unroll
    for (int rb=0;rb<4;rb++){
      bf16x8 a = *(const bf16x8*)(T1 + swz<64>(rb*16 + lrow, ks*64 + lgrp*16));
      #pragma unroll
      for (int f=0;f<2;f++)
        acc1[rb][f] = __builtin_amdgcn_mfma_f32_16x16x32_bf16(a, bb[f], acc1[rb][f], 0,0,0);
    }
  }

  // store rounded raw t2 (CSR row order) + stats on rounded values
  float s[2]={0.f,0.f}, ss[2]={0.f,0.f};
  #pragma unroll
  for (int rb=0;rb<4;rb++)
    #pragma unroll
    for (int f=0;f<2;f++)
      #pragma unroll
      for (int r=0;r<4;r++){
        int gr = rowbase + rb*16 + 4*lgrp + r;
        if (gr < n){
          ushort h = f2bf(acc1[rb][f][r]);
          t2[(size_t)gr*128 + w*32 + 16*f + lrow] = h;
          float fr = bf2f(h);
          s[f] += fr; ss[f] += fr*fr;
        }
      }
  __syncthreads();
  float* ssum = (float*)smem;
  ssum[t] = 0.f;
  __syncthreads();
  #pragma unroll
  for (int f=0;f<2;f++){
    int j = w*32 + 16*f + lrow;
    atomicAdd(&ssum[j], s[f]); atomicAdd(&ssum[128+j], ss[f]);
  }
  __syncthreads();
  float* gsl = slices + (size_t)(blockIdx.x & (SLICES-1))*256;
  atomicAdd(&gsl[t], ssum[t]);
}

// shared T2 staging: t2 (raw bf16) -> bn2 affine + relu -> LDS swz<128>
__device__ __forceinline__ void stage_T2(char* T2, const ushort* __restrict__ t2,
    const float* __restrict__ ac2, int rowbase, int t, int n){
  for (int e = t; e < 1024; e += 256){
    int row = e >> 4, k8 = (e & 15) << 3;
    int gr = rowbase + row;
    bf16x8 v = {};
    if (gr < n) v = *(const bf16x8*)(t2 + (size_t)gr*128 + k8);
    float4 A0 = *(const float4*)(ac2 + k8),       A1 = *(const float4*)(ac2 + k8 + 4);
    float4 C0 = *(const float4*)(ac2 + 128 + k8), C1 = *(const float4*)(ac2 + 128 + k8 + 4);
    float Av[8] = {A0.x,A0.y,A0.z,A0.w,A1.x,A1.y,A1.z,A1.w};
    float Cv[8] = {C0.x,C0.y,C0.z,C0.w,C1.x,C1.y,C1.z,C1.w};
    bf16x8 o;
    #pragma unroll
    for (int i=0;i<8;i++){
      float f = (gr < n) ? fmaxf(fmaf(bf2f((ushort)v[i]), Av[i], Cv[i]), 0.f) : 0.f;
      o[i] = f2bf(f);
    }
    *(bf16x8*)(T2 + swz<128>(row, k8*2)) = o;
  }
}

// pass 2: t2 -> stage3 -> t3 stats (16.5KB LDS, 1 barrier)
__global__ __launch_bounds__(256,2) void k_stage3(
    const ushort* __restrict__ t2, const float* __restrict__ ac2,
    const ushort* __restrict__ w3f, float* __restrict__ slices, int n){
  __shared__ __align__(16) char smem[16384];
  char* T2 = smem;
  int t = threadIdx.x;
  int lane = t & 63, w = t >> 6;
  int lrow = lane & 15, lgrp = lane >> 4;
  int rowbase = blockIdx.x * 64;
  stage_T2(T2, t2, ac2, rowbase, t, n);
  __syncthreads();

  f32x4 acc2[4][4] = {};
  #pragma unroll
  for (int ks=0; ks<4; ks++){
    bf16x8 bb[4];
    #pragma unroll
    for (int f=0;f<4;f++)
      bb[f] = *(const bf16x8*)(w3f + (size_t)((ks*16 + 4*w + f)*64 + lane)*8);
    #pragma unroll
    for (int rb=0;rb<4;rb++){
      bf16x8 a = *(const bf16x8*)(T2 + swz<128>(rb*16 + lrow, ks*64 + lgrp*16));
      #pragma unroll
      for (int f=0;f<4;f++)
        acc2[rb][f] = __builtin_amdgcn_mfma_f32_16x16x32_bf16(a, bb[f], acc2[rb][f], 0,0,0);
    }
  }
  __syncthreads();
  float* ssum = (float*)smem;
  for (int e=t; e<512; e+=256) ssum[e] = 0.f;
  __syncthreads();
  #pragma unroll
  for (int f=0;f<4;f++){
    float s=0.f, ss=0.f;
    #pragma unroll
    for (int rb=0;rb<4;rb++)
      #pragma unroll
      for (int r=0;r<4;r++){ float v=acc2[rb][f][r]; s+=v; ss+=v*v; }
    int j = 64*w + 16*f + lrow;
    atomicAdd(&ssum[j], s); atomicAdd(&ssum[256+j], ss);
  }
  __syncthreads();
  float* gsl = slices + (size_t)(blockIdx.x & (SLICES-1))*512;
  for (int e=t; e<512; e+=256) atomicAdd(&gsl[e], ssum[e]);
}

// pass 3: t2 -> stage3 -> bn3+relu -> stage4 -> y4
__global__ __launch_bounds__(256,2) void k_stage34(
    const ushort* __restrict__ t2, const float* __restrict__ ac2,
    const ushort* __restrict__ w3f, const float* __restrict__ ac3,
    const ushort* __restrict__ w4f, const float* __restrict__ b4,
    ushort* __restrict__ y4, int n){
  __shared__ __align__(16) char smem[32768];
  char* T2 = smem + 16384;          // upper 16KB
  char* X3 = smem;                  // full 32KB (after barrier)
  int t = threadIdx.x;
  int lane = t & 63, w = t >> 6;
  int lrow = lane & 15, lgrp = lane >> 4;
  int rowbase = blockIdx.x * 64;
  stage_T2(T2, t2, ac2, rowbase, t, n);
  __syncthreads();

  f32x4 acc2[4][4] = {};
  #pragma unroll
  for (int ks=0; ks<4; ks++){
    bf16x8 bb[4];
    #pragma unroll
    for (int f=0;f<4;f++)
      bb[f] = *(const bf16x8*)(w3f + (size_t)((ks*16 + 4*w + f)*64 + lane)*8);
    #pragma unroll
    for (int rb=0;rb<4;rb++){
      bf16x8 a = *(const bf16x8*)(T2 + swz<128>(rb*16 + lrow, ks*64 + lgrp*16));
      #pragma unroll
      for (int f=0;f<4;f++)
        acc2[rb][f] = __builtin_amdgcn_mfma_f32_16x16x32_bf16(a, bb[f], acc2[rb][f], 0,0,0);
    }
  }
  __syncthreads();   // T2 dead -> X3 takes full LDS

  #pragma unroll
  for (int f=0;f<4;f++){
    int j = 64*w + 16*f + lrow;
    float a3 = ac3[j], c3 = ac3[256+j];
    #pragma unroll
    for (int rb=0;rb<4;rb++)
      #pragma unroll
      for (int r=0;r<4;r++){
        int row = rb*16 + 4*lgrp + r;
        float v = fmaxf(fmaf(acc2[rb][f][r], a3, c3), 0.f);
        if (rowbase + row >= n) v = 0.f;
        *(ushort*)(X3 + swz<256>(row, j*2)) = f2bf(v);
      }
  }
  __syncthreads();

  f32x4 acc3[4] = {};
  #pragma unroll
  for (int ks=0; ks<8; ks++){
    bf16x8 b = *(const bf16x8*)(w4f + (size_t)((ks*4 + w)*64 + lane)*8);
    #pragma unroll
    for (int rb=0;rb<4;rb++){
      bf16x8 a = *(const bf16x8*)(X3 + swz<256>(rb*16 + lrow, ks*64 + lgrp*16));
      acc3[rb] = __builtin_amdgcn_mfma_f32_16x16x32_bf16(a, b, acc3[rb], 0,0,0);
    }
  }
  {
    int j = w*16 + lrow;
    float bias4 = b4[j];
    #pragma unroll
    for (int rb=0;rb<4;rb++)
      #pragma unroll
      for (int r=0;r<4;r++){
        int gr = rowbase + 16*rb + 4*lgrp + r;
        if (gr < n) y4[(size_t)gr*64 + j] = f2bf(acc3[rb][r] + bias4);
      }
  }
}

// ================= FALLBACK PATH (round-9 chain, unchanged) =================
template<int DEPTH>
__global__ __launch_bounds__(256,2) void k_chain(
    const float* __restrict__ feats, const float* __restrict__ ac0,
    const ushort* __restrict__ w1f, const float* __restrict__ ac1,
    const ushort* __restrict__ w2f, const float* __restrict__ ac2,
    const ushort* __restrict__ w3f, const float* __restrict__ ac3,
    const ushort* __restrict__ w4f, const float* __restrict__ b4,
    const unsigned* __restrict__ csr, ushort* __restrict__ y4,
    float* __restrict__ slices, int n){
  constexpr int SMEM = (DEPTH==2) ? 12288 : (DEPTH==3) ? 28672 : 32768;
  __shared__ __align__(16) char smem[SMEM];
  __shared__ unsigned rid_s[64];
  char* X0 = smem;
  int t = threadIdx.x;
  int lane = t & 63, w = t >> 6;
  int lrow = lane & 15, lgrp = lane >> 4;
  int rowbase = blockIdx.x * 64;
  bf16x8 b1 = *(const bf16x8*)(w1f + (size_t)(w*64 + lane)*8);
  if constexpr (DEPTH == 4){
    if (t < 64){
      int gr = rowbase + t;
      rid_s[t] = (gr < n) ? csr[gr] : 0u;
    }
    __syncthreads();
  }
  for (int e = t; e < 2048; e += 256){
    int row = e >> 5, k = e & 31;
    int gr = rowbase + row;
    size_t rid = (DEPTH == 4) ? (size_t)rid_s[row] : (size_t)gr;
    float v = (k < 9 && gr < n) ? fmaf(feats[rid*9 + k], ac0[k], ac0[9+k]) : 0.f;
    *(ushort*)(X0 + swz<32>(row, k*2)) = f2bf(v);
  }
  __syncthreads();
  f32x4 acc0[4] = {};
  #pragma unroll
  for (int rb = 0; rb < 4; rb++){
    bf16x8 a = *(const bf16x8*)(X0 + swz<32>(rb*16 + lrow, lgrp*16));
    acc0[rb] = __builtin_amdgcn_mfma_f32_16x16x32_bf16(a, b1, acc0[rb], 0,0,0);
  }
  char* T1 = smem + 4096;
  {
    int j = w*16 + lrow;
    float a1 = ac1[j], c1 = ac1[64+j];
    #pragma unroll
    for (int rb=0;rb<4;rb++)
      #pragma unroll
      for (int r=0;r<4;r++){
        int row = rb*16 + 4*lgrp + r;
        float v = fmaxf(fmaf(acc0[rb][r], a1, c1), 0.f);
        if (rowbase + row >= n) v = 0.f;
        *(ushort*)(T1 + swz<64>(row, j*2)) = f2bf(v);
      }
  }
  __syncthreads();
  f32x4 acc1[4][2] = {};
  #pragma unroll
  for (int ks=0; ks<2; ks++){
    bf16x8 bb[2];
    #pragma unroll
    for (int f=0;f<2;f++)
      bb[f] = *(const bf16x8*)(w2f + (size_t)((ks*8 + 2*w + f)*64 + lane)*8);
    #pragma unroll
    for (int rb=0;rb<4;rb++){
      bf16x8 a = *(const bf16x8*)(T1 + swz<64>(rb*16 + lrow, ks*64 + lgrp*16));
      #pragma unroll
      for (int f=0;f<2;f++)
        acc1[rb][f] = __builtin_amdgcn_mfma_f32_16x16x32_bf16(a, bb[f], acc1[rb][f], 0,0,0);
    }
  }
  if constexpr (DEPTH == 2){
    float s[2]={0.f,0.f}, ss[2]={0.f,0.f};
    #pragma unroll
    for (int rb=0;rb<4;rb++)
      #pragma unroll
      for (int f=0;f<2;f++)
        #pragma unroll
        for (int r=0;r<4;r++){ float v=acc1[rb][f][r]; s[f]+=v; ss[f]+=v*v; }
    __syncthreads();
    float* ssum = (float*)smem;
    ssum[t] = 0.f;
    __syncthreads();
    #pragma unroll
    for (int f=0;f<2;f++){
      int j = w*32 + 16*f + lrow;
      atomicAdd(&ssum[j], s[f]); atomicAdd(&ssum[128+j], ss[f]);
    }
    __syncthreads();
    float* gsl = slices + (size_t)(blockIdx.x & (SLICES-1))*256;
    atomicAdd(&gsl[t], ssum[t]);
    return;
  }
  if constexpr (DEPTH >= 3){
  char* T2 = smem + 12288;
  #pragma unroll
  for (int f=0;f<2;f++){
    int j = w*32 + 16*f + lrow;
    float a2 = ac2[j], c2 = ac2[128+j];
    #pragma unroll
    for (int rb=0;rb<4;rb++)
      #pragma unroll
      for (int r=0;r<4;r++){
        int row = rb*16 + 4*lgrp + r;
        float v = fmaxf(fmaf(acc1[rb][f][r], a2, c2), 0.f);
        if (rowbase + row >= n) v = 0.f;
        *(ushort*)(T2 + swz<128>(row, j*2)) = f2bf(v);
      }
  }
  __syncthreads();
  if constexpr (DEPTH == 3){
    float s3[2][2], ss3[2][2];
    #pragma unroll
    for (int h=0; h<2; h++){
      f32x4 acc2[4][2] = {};
      #pragma unroll
      for (int ks=0; ks<4; ks++){
        bf16x8 bb[2];
        #pragma unroll
        for (int f=0;f<2;f++)
          bb[f] = *(const bf16x8*)(w3f + (size_t)((ks*16 + 4*w + 2*h + f)*64 + lane)*8);
        #pragma unroll
        for (int rb=0;rb<4;rb++){
          bf16x8 a = *(const bf16x8*)(T2 + swz<128>(rb*16 + lrow, ks*64 + lgrp*16));
          #pragma unroll
          for (int f=0;f<2;f++)
            acc2[rb][f] = __builtin_amdgcn_mfma_f32_16x16x32_bf16(a, bb[f], acc2[rb][f], 0,0,0);
        }
      }
      #pragma unroll
      for (int f=0;f<2;f++){
        float s=0.f, ss=0.f;
        #pragma unroll
        for (int rb=0;rb<4;rb++)
          #pragma unroll
          for (int r=0;r<4;r++){ float v=acc2[rb][f][r]; s+=v; ss+=v*v; }
        s3[h][f]=s; ss3[h][f]=ss;
      }
    }
    __syncthreads();
    float* ssum = (float*)smem;
    for (int e=t; e<512; e+=256) ssum[e] = 0.f;
    __syncthreads();
    #pragma unroll
    for (int h=0;h<2;h++)
      #pragma unroll
      for (int f=0;f<2;f++){
        int j = 64*w + 32*h + 16*f + lrow;
        atomicAdd(&ssum[j], s3[h][f]); atomicAdd(&ssum[256+j], ss3[h][f]);
      }
    __syncthreads();
    float* gsl = slices + (size_t)(blockIdx.x & (SLICES-1))*512;
    for (int e=t; e<512; e+=256) atomicAdd(&gsl[e], ssum[e]);
    return;
  }
  if constexpr (DEPTH == 4){
  f32x4 acc2[4][4] = {};
  #pragma unroll
  for (int ks=0; ks<4; ks++){
    bf16x8 bb[4];
    #pragma unroll
    for (int f=0;f<4;f++)
      bb[f] = *(const bf16x8*)(w3f + (size_t)((ks*16 + 4*w + f)*64 + lane)*8);
    #pragma unroll
    for (int rb=0;rb<4;rb++){
      bf16x8 a = *(const bf16x8*)(T2 + swz<128>(rb*16 + lrow, ks*64 + lgrp*16));
      #pragma unroll
      for (int f=0;f<4;f++)
        acc2[rb][f] = __builtin_amdgcn_mfma_f32_16x16x32_bf16(a, bb[f], acc2[rb][f], 0,0,0);
    }
  }
  __syncthreads();
  char* X3 = smem;
  #pragma unroll
  for (int f=0;f<4;f++){
    int j = 64*w + 16*f + lrow;
    float a3 = ac3[j], c3 = ac3[256+j];
    #pragma unroll
    for (int rb=0;rb<4;rb++)
      #pragma unroll
      for (int r=0;r<4;r++){
        int row = rb*16 + 4*lgrp + r;
        float v = fmaxf(fmaf(acc2[rb][f][r], a3, c3), 0.f);
        if (rowbase + row >= n) v = 0.f;
        *(ushort*)(X3 + swz<256>(row, j*2)) = f2bf(v);
      }
  }
  __syncthreads();
  f32x4 acc3[4] = {};
  #pragma unroll
  for (int ks=0; ks<8; ks++){
    bf16x8 b = *(const bf16x8*)(w4f + (size_t)((ks*4 + w)*64 + lane)*8);
    #pragma unroll
    for (int rb=0;rb<4;rb++){
      bf16x8 a = *(const bf16x8*)(X3 + swz<256>(rb*16 + lrow, ks*64 + lgrp*16));
      acc3[rb] = __builtin_amdgcn_mfma_f32_16x16x32_bf16(a, b, acc3[rb], 0,0,0);
    }
  }
  {
    int j = w*16 + lrow;
    float bias4 = b4[j];
    #pragma unroll
    for (int rb=0;rb<4;rb++)
      #pragma unroll
      for (int r=0;r<4;r++){
        int gr = rowbase + 16*rb + 4*lgrp + r;
        if (gr < n){
          y4[(size_t)gr*64 + j] = f2bf(acc3[rb][r] + bias4);
        }
      }
  }
  } // DEPTH==4
  } // DEPTH>=3
}

// ---------------- pool: lane = channel, contiguous CSR rows, 8 voxels/wave ----------------
__global__ __launch_bounds__(256) void k_pool(const ushort* __restrict__ y4,
    const unsigned* __restrict__ vst, const unsigned* __restrict__ vct,
    const unsigned* __restrict__ boff, const float* __restrict__ wp,
    const float* __restrict__ bp, float* __restrict__ out, int n){
  __shared__ float wpsT[1024];      // [16][64]: wpsT[j*64+ch] = wp[ch][j]
  __shared__ float sm[4][64];
  int t = threadIdx.x, w = t >> 6, lane = t & 63;
  for (int e=t; e<1024; e+=256){
    int j = e >> 6, ch = e & 63;
    wpsT[e] = wp[ch*16 + j];
  }
  __syncthreads();
  unsigned M = boff[216];
  int base = blockIdx.x*(4*VPW) + w*VPW;
  if (base >= (int)M) return;
  float bpv = (lane < 16) ? bp[lane] : 0.f;
  int q = lane >> 4, j = lane & 15;
  int vend = (int)M - base; if (vend > VPW) vend = VPW;
  for (int v = 0; v < vend; v++){
    int r = base + v;
    unsigned st = vst[r], c = vct[r];
    const ushort* row = y4 + (size_t)st*64 + lane;
    float m = bf2f(row[0]);
    #pragma unroll 4
    for (unsigned pp = 1; pp < c; pp++)
      m = fmaxf(m, bf2f(row[(size_t)pp*64]));
    sm[w][lane] = m;
    float acc = 0.f;
    #pragma unroll
    for (int i=0;i<16;i++) acc = fmaf(sm[w][q*16+i], wpsT[j*64 + q*16+i], acc);
    acc += __shfl_xor(acc, 16, 64);
    acc += __shfl_xor(acc, 32, 64);
    if (lane < 16) out[(size_t)r*16 + lane] = fmaxf(acc + bpv, 0.f);
  }
}

// ---------------- padding rows: out = relu(bp), unq = -1 ----------------
__global__ __launch_bounds__(256) void k_fill(const unsigned* __restrict__ boff,
    const float* __restrict__ bp, float* __restrict__ out,
    float* __restrict__ unq, int n){
  int r = blockIdx.x*256 + threadIdx.x;
  if (r >= n) return;
  unsigned M = boff[216];
  if ((unsigned)r < M) return;
  #pragma unroll
  for (int j=0;j<16;j++) out[(size_t)r*16 + j] = fmaxf(bp[j], 0.f);
  unq[3*(size_t)r+0] = -1.f; unq[3*(size_t)r+1] = -1.f; unq[3*(size_t)r+2] = -1.f;
}

extern "C" void kernel_launch(void* const* d_in, const int* in_sizes, int n_in,
                              void* d_out, int out_size, void* d_ws, size_t ws_size,
                              hipStream_t stream){
  (void)n_in; (void)out_size;
  const float* feats  = (const float*)d_in[0];
  const int*   coords = (const int*)d_in[1];
  const float* g0=(const float*)d_in[2];  const float* bb0=(const float*)d_in[3];
  const float* g1=(const float*)d_in[4];  const float* bb1=(const float*)d_in[5];
  const float* g2=(const float*)d_in[6];  const float* bb2=(const float*)d_in[7];
  const float* g3=(const float*)d_in[8];  const float* bb3=(const float*)d_in[9];
  const float* w1=(const float*)d_in[10];
  const float* w2=(const float*)d_in[12];
  const float* w3=(const float*)d_in[14];
  const float* w4=(const float*)d_in[16]; const float* b4=(const float*)d_in[17];
  const float* wp=(const float*)d_in[18]; const float* bp=(const float*)d_in[19];
  int n = in_sizes[0]/9;

  char* ws = (char*)d_ws;
  size_t off = 0;
  auto alloc = [&](size_t bytes){ size_t o = off; off = (off + bytes + 255) & ~(size_t)255; return o; };
  size_t o_cnt  = alloc((size_t)NKEYS*4);            // zeroed
  size_t o_cur  = alloc((size_t)NKEYS*4);            // zeroed (csr cursors)
  size_t o_sl0  = alloc((size_t)SLICES*54*4);        // zeroed
  size_t o_sl2  = alloc((size_t)SLICES*256*4);       // zeroed
  size_t o_sl3  = alloc((size_t)SLICES*512*4);       // zeroed
  size_t zero_end = off;
  size_t o_rloc = alloc((size_t)NKEYS*4);
  size_t o_ploc = alloc((size_t)NKEYS*4);
  size_t o_bsum = alloc(256*4);
  size_t o_boff = alloc(256*4);
  size_t o_ac0  = alloc(18*4);
  size_t o_ac1  = alloc(128*4);
  size_t o_ac2  = alloc(256*4);
  size_t o_ac3  = alloc(512*4);
  size_t o_w1f  = alloc(2048*2);
  size_t o_w2f  = alloc(8192*2);
  size_t o_w3f  = alloc(32768*2);
  size_t o_w4f  = alloc(16384*2);
  size_t o_csr  = alloc((size_t)n*4);
  size_t o_vst  = alloc((size_t)n*4);
  size_t o_vct  = alloc((size_t)n*4);
  size_t o_y4   = alloc((size_t)n*64*2);
  size_t off_base = off;
  size_t o_t2   = alloc((size_t)n*128*2);            // 64MB, fast path only
  size_t off_full = off;
  if (ws_size < off_base) return;                    // clean fail if ws too small
  bool bigws = (ws_size >= off_full);

  unsigned* cnt  = (unsigned*)(ws + o_cnt);
  unsigned* cursor = (unsigned*)(ws + o_cur);
  unsigned* rloc = (unsigned*)(ws + o_rloc);
  unsigned* ploc = (unsigned*)(ws + o_ploc);
  unsigned* bsum = (unsigned*)(ws + o_bsum);
  unsigned* boff = (unsigned*)(ws + o_boff);
  float* sl0 = (float*)(ws + o_sl0);
  float* sl2 = (float*)(ws + o_sl2);
  float* sl3 = (float*)(ws + o_sl3);
  float* ac0 = (float*)(ws + o_ac0);
  float* ac1 = (float*)(ws + o_ac1);
  float* ac2 = (float*)(ws + o_ac2);
  float* ac3 = (float*)(ws + o_ac3);
  ushort* w1f = (ushort*)(ws + o_w1f);
  ushort* w2f = (ushort*)(ws + o_w2f);
  ushort* w3f = (ushort*)(ws + o_w3f);
  ushort* w4f = (ushort*)(ws + o_w4f);
  unsigned* csr = (unsigned*)(ws + o_csr);
  unsigned* vst = (unsigned*)(ws + o_vst);
  unsigned* vct = (unsigned*)(ws + o_vct);
  ushort* y4 = (ushort*)(ws + o_y4);
  ushort* t2 = (ushort*)(ws + o_t2);

  float* out_pool = (float*)d_out;
  float* out_unq  = out_pool + (size_t)n*16;

  {
    size_t n16 = zero_end/16;
    int zb = (int)((n16 + 255)/256); if (zb > 2048) zb = 2048;
    k_zero<<<zb,256,0,stream>>>((uint4*)ws, n16);
  }

  // weight prep (bf16, B-fragment order)
  k_wprep<<<8,256,0,stream>>>(w1, w1f, 9, 64);
  k_wprep<<<32,256,0,stream>>>(w2, w2f, 64, 128);
  k_wprep<<<128,256,0,stream>>>(w3, w3f, 128, 256);
  k_wprep<<<64,256,0,stream>>>(w4, w4f, 256, 64);

  int nb = (n + 255)/256;
  k_keys<<<nb,256,0,stream>>>(coords, cnt, n);
  k_scan1<<<NKEYS/1024,256,0,stream>>>(cnt, rloc, ploc, bsum);
  k_scan2<<<1,128,0,stream>>>(bsum, boff);
  k_unq<<<(NKEYS+255)/256,256,0,stream>>>(cnt, rloc, ploc, boff, out_unq, vst, vct);
  k_csr<<<nb,256,0,stream>>>(coords, ploc, boff, cursor, csr, n);

  // feats moments -> ac0 + analytic ac1
  k_stats0x<<<512,256,0,stream>>>(feats, sl0, n);
  k_fin01<<<1,256,0,stream>>>(sl0, 1.f/(float)n, g0, bb0, g1, bb1, w1, ac0, ac1);

  int gb = (n+63)/64;
  if (bigws){
    k_chain12<<<gb,256,0,stream>>>(feats, ac0, w1f, ac1, w2f, csr, t2, sl2, n);
    k_fin<<<2,256,0,stream>>>(sl2, 128, 1.f/(float)n, g2, bb2, ac2);
    k_stage3<<<gb,256,0,stream>>>(t2, ac2, w3f, sl3, n);
    k_fin<<<4,256,0,stream>>>(sl3, 256, 1.f/(float)n, g3, bb3, ac3);
    k_stage34<<<gb,256,0,stream>>>(t2, ac2, w3f, ac3, w4f, b4, y4, n);
  } else {
    k_chain<2><<<gb,256,0,stream>>>(feats, ac0, w1f, ac1, w2f, ac2, w3f, ac3, w4f, b4, nullptr, nullptr, sl2, n);
    k_fin<<<2,256,0,stream>>>(sl2, 128, 1.f/(float)n, g2, bb2, ac2);
    k_chain<3><<<gb,256,0,stream>>>(feats, ac0, w1f, ac1, w2f, ac2, w3f, ac3, w4f, b4, nullptr, nullptr, sl3, n);
    k_fin<<<4,256,0,stream>>>(sl3, 256, 1.f/(float)n, g3, bb3, ac3);
    k_chain<4><<<gb,256,0,stream>>>(feats, ac0, w1f, ac1, w2f, ac2, w3f, ac3, w4f, b4, csr, y4, nullptr, n);
  }

  int maxv = (n < NKEYS) ? n : NKEYS;
  k_pool<<<(maxv + 4*VPW - 1)/(4*VPW),256,0,stream>>>(y4, vst, vct, boff, wp, bp, out_pool, n);
  k_fill<<<nb,256,0,stream>>>(boff, bp, out_pool, out_unq, n);
}